// Round 15
// baseline (238.520 us; speedup 1.0000x reference)
//
#include <hip/hip_runtime.h>
#include <stdint.h>

#define B_ 2
#define S_ 2048
#define E_ 1024
#define H_ 16
#define HD_ 64
#define FF_ 4096
#define M_ 4096   // B*S
#define LOG2E_ 1.44269504f

typedef short bf16x8 __attribute__((ext_vector_type(8)));
typedef float f32x4  __attribute__((ext_vector_type(4)));
typedef short shortx4 __attribute__((ext_vector_type(4)));

#define MFMA16(a,b,c) __builtin_amdgcn_mfma_f32_16x16x32_bf16(a,b,c,0,0,0)

__device__ __forceinline__ short f2bf(float f) {
  uint32_t u = __builtin_bit_cast(uint32_t, f);
  u += 0x7fffu + ((u >> 16) & 1u);
  return (short)(u >> 16);
}
__device__ __forceinline__ float bf2f(short b) {
  uint32_t u = ((uint32_t)(uint16_t)b) << 16;
  return __builtin_bit_cast(float, u);
}
__device__ __forceinline__ float exp2_hw(float x) {
  float r;
  asm("v_exp_f32 %0, %1" : "=v"(r) : "v"(x));
  return r;
}

// DPP row-rotate (16-lane row), VALU-pipe cross-lane: ROW_ROR:N = 0x120|N
template<int CTRL>
__device__ __forceinline__ float dpp_ror(float x) {
  return __builtin_bit_cast(float,
    __builtin_amdgcn_update_dpp(0, __builtin_bit_cast(int, x), CTRL, 0xF, 0xF, true));
}
__device__ __forceinline__ float dpp_max16(float v) {
  v = fmaxf(v, dpp_ror<0x128>(v));
  v = fmaxf(v, dpp_ror<0x124>(v));
  v = fmaxf(v, dpp_ror<0x122>(v));
  v = fmaxf(v, dpp_ror<0x121>(v));
  return v;
}
__device__ __forceinline__ float dpp_sum16(float v) {
  v += dpp_ror<0x128>(v);
  v += dpp_ror<0x124>(v);
  v += dpp_ror<0x122>(v);
  v += dpp_ror<0x121>(v);
  return v;
}

// async global->LDS, 16B per lane, wave-uniform LDS base + lane*16 (per-lane global src)
#define GLDS16(g, l) __builtin_amdgcn_global_load_lds( \
    (const __attribute__((address_space(1))) unsigned int*)(g), \
    (__attribute__((address_space(3))) unsigned int*)(l), 16, 0, 0)

// ---------------------------------------------------------------- fused cast f32->bf16 (all 5 arrays)
__global__ void cast_all(const float* __restrict__ x, const float* __restrict__ wkqv,
                         const float* __restrict__ wo, const float* __restrict__ wup,
                         const float* __restrict__ wdown,
                         short* __restrict__ xb, short* __restrict__ wkqvb,
                         short* __restrict__ wob, short* __restrict__ wupb,
                         short* __restrict__ wdownb) {
  const int stride = gridDim.x * blockDim.x;
  for (int i = blockIdx.x * blockDim.x + threadIdx.x; i < 4194304; i += stride) {
    const int e = i << 2;
    const float* src; short* dst; int off;
    if (e < 4194304)       { src = x;     dst = xb;     off = e; }
    else if (e < 7340032)  { src = wkqv;  dst = wkqvb;  off = e - 4194304; }
    else if (e < 8388608)  { src = wo;    dst = wob;    off = e - 7340032; }
    else if (e < 12582912) { src = wup;   dst = wupb;   off = e - 8388608; }
    else                   { src = wdown; dst = wdownb; off = e - 12582912; }
    float4 v = *(const float4*)(src + off);
    shortx4 o;
    o.x = f2bf(v.x); o.y = f2bf(v.y); o.z = f2bf(v.z); o.w = f2bf(v.w);
    *(shortx4*)(dst + off) = o;
  }
}

// ---------------------------------------------------------------- GEMM 256xBN, BK=64, 8 waves
// Phase-structured (T2+T3+T4+T5), FULL-TILE prefetch: all of tile t+1's
// global_load_lds issued at phase a; vmcnt(TOT) waits only tile t's loads.
// XOR-swizzled LDS (phys 16B-slot = logical ^ (row&7), pre-swizzled source).
// BN in {256,128}. SK: split-K (blockIdx.y slice -> C0/C1). EPI=1: bias+relu.
template<int BN, int SK, int EPI, typename OutT>
__global__ __launch_bounds__(512, 2) void gemm256_bt(
    const short* __restrict__ A, const short* __restrict__ Bw,
    OutT* __restrict__ C0, OutT* __restrict__ C1, const float* __restrict__ bias,
    int M, int N, int K)
{
  constexpr int WCN  = BN / 4;       // per-wave N extent (64 or 32)
  constexpr int NJ   = WCN / 16;     // j-frags per wave (4 or 2)
  constexpr int NJH  = NJ / 2;       // j-frags per phase (2 or 1)
  constexpr int ISSB = BN / 64;      // B stage issues/thread (4 or 2)

  __shared__ short Al[2][256 * 64];
  __shared__ short Bl[2][BN * 64];
  const int tid = threadIdx.x;
  const int w = tid >> 6, lane = tid & 63;
  const int lr = lane & 15, lg = lane >> 4;
  const int ntiles = N / BN;
  const int nwg = gridDim.x;
  const int bid = blockIdx.x;
  const int swz = (bid & 7) * (nwg >> 3) + (bid >> 3);
  const int tn = swz % ntiles, tm = swz / ntiles;
  const int m0 = tm << 8, n0 = tn * BN;
  const int wrm = (w >> 2) << 7;       // 0 / 128
  const int wcn = (w & 3) * WCN;

  const int kper = K / SK;
  const int kbeg = (SK > 1) ? (int)blockIdx.y * kper : 0;
  const int T = kper >> 6;
  OutT* __restrict__ C = (SK > 1 && blockIdx.y) ? C1 : C0;

  // staging: issue i stages chunk c = w + i*8 (8 rows x 128B, 64 lanes x 16B)
  const int srow = lane >> 3;
  const int scol = ((lane & 7) ^ srow) << 3;   // pre-swizzled source col (shorts)
  const short* Ag[4]; const short* Bg[ISSB];
  #pragma unroll
  for (int i = 0; i < 4; ++i)
    Ag[i] = A + (size_t)(m0 + (w + i * 8) * 8 + srow) * K + kbeg + scol;
  #pragma unroll
  for (int i = 0; i < ISSB; ++i)
    Bg[i] = Bw + (size_t)(n0 + (w + i * 8) * 8 + srow) * K + kbeg + scol;

  f32x4 acc[8][NJ] = {};

  // prologue: tile 0 -> buf 0
  #pragma unroll
  for (int i = 0; i < 4; ++i) GLDS16(Ag[i], &Al[0][(w + i * 8) * 512]);
  #pragma unroll
  for (int i = 0; i < ISSB; ++i) GLDS16(Bg[i], &Bl[0][(w + i * 8) * 512]);

  for (int t = 0; t < T; ++t) {
    const int buf = t & 1;
    const bool more = (t + 1 < T);
    const int k1 = (t + 1) << 6;

    bf16x8 af[8], bfLo[NJH * 2], bfHi[NJH * 2];
    const int ph0 = lg ^ (lr & 7);        // ks=0 swizzled slot
    const int ph1 = (4 + lg) ^ (lr & 7);  // ks=1

    // ---- phase a: issue ALL of t+1; vmcnt(TOT) drains tile t's loads
    if (more) {
      #pragma unroll
      for (int i = 0; i < 4; ++i) GLDS16(Ag[i] + k1, &Al[buf ^ 1][(w + i * 8) * 512]);
      #pragma unroll
      for (int i = 0; i < ISSB; ++i) GLDS16(Bg[i] + k1, &Bl[buf ^ 1][(w + i * 8) * 512]);
      if constexpr (ISSB == 4) asm volatile("s_waitcnt vmcnt(8)" ::: "memory");
      else                     asm volatile("s_waitcnt vmcnt(6)" ::: "memory");
    } else {
      asm volatile("s_waitcnt vmcnt(0)" ::: "memory");
    }
    __builtin_amdgcn_sched_barrier(0);
    __builtin_amdgcn_s_barrier();

    #pragma unroll
    for (int i = 0; i < 4; ++i) {
      const int R = wrm + i * 16 + lr;
      af[i * 2]     = *(const bf16x8*)&Al[buf][R * 64 + ph0 * 8];
      af[i * 2 + 1] = *(const bf16x8*)&Al[buf][R * 64 + ph1 * 8];
    }
    #pragma unroll
    for (int j = 0; j < NJH; ++j) {
      const int R = wcn + j * 16 + lr;
      bfLo[j * 2]     = *(const bf16x8*)&Bl[buf][R * 64 + ph0 * 8];
      bfLo[j * 2 + 1] = *(const bf16x8*)&Bl[buf][R * 64 + ph1 * 8];
    }
    __builtin_amdgcn_s_setprio(1);
    #pragma unroll
    for (int i = 0; i < 4; ++i)
      #pragma unroll
      for (int j = 0; j < NJH; ++j) {
        acc[i][j] = MFMA16(af[i * 2],     bfLo[j * 2],     acc[i][j]);
        acc[i][j] = MFMA16(af[i * 2 + 1], bfLo[j * 2 + 1], acc[i][j]);
      }
    __builtin_amdgcn_s_setprio(0);
    __builtin_amdgcn_s_barrier();

    // ---- phase b: reads B j-hi; MFMA i0-3 x j-hi
    #pragma unroll
    for (int j = 0; j < NJH; ++j) {
      const int R = wcn + (j + NJH) * 16 + lr;
      bfHi[j * 2]     = *(const bf16x8*)&Bl[buf][R * 64 + ph0 * 8];
      bfHi[j * 2 + 1] = *(const bf16x8*)&Bl[buf][R * 64 + ph1 * 8];
    }
    __builtin_amdgcn_s_setprio(1);
    #pragma unroll
    for (int i = 0; i < 4; ++i)
      #pragma unroll
      for (int j = 0; j < NJH; ++j) {
        acc[i][j + NJH] = MFMA16(af[i * 2],     bfHi[j * 2],     acc[i][j + NJH]);
        acc[i][j + NJH] = MFMA16(af[i * 2 + 1], bfHi[j * 2 + 1], acc[i][j + NJH]);
      }
    __builtin_amdgcn_s_setprio(0);
    __builtin_amdgcn_s_barrier();

    // ---- phase c: reads A i4-7; MFMA i4-7 x j-hi
    #pragma unroll
    for (int i = 0; i < 4; ++i) {
      const int R = wrm + (i + 4) * 16 + lr;
      af[i * 2]     = *(const bf16x8*)&Al[buf][R * 64 + ph0 * 8];
      af[i * 2 + 1] = *(const bf16x8*)&Al[buf][R * 64 + ph1 * 8];
    }
    __builtin_amdgcn_s_setprio(1);
    #pragma unroll
    for (int i = 0; i < 4; ++i)
      #pragma unroll
      for (int j = 0; j < NJH; ++j) {
        acc[i + 4][j + NJH] = MFMA16(af[i * 2],     bfHi[j * 2],     acc[i + 4][j + NJH]);
        acc[i + 4][j + NJH] = MFMA16(af[i * 2 + 1], bfHi[j * 2 + 1], acc[i + 4][j + NJH]);
      }
    __builtin_amdgcn_s_setprio(0);
    __builtin_amdgcn_s_barrier();

    // ---- phase d: MFMA i4-7 x j-lo (bfLo still live)
    __builtin_amdgcn_s_setprio(1);
    #pragma unroll
    for (int i = 0; i < 4; ++i)
      #pragma unroll
      for (int j = 0; j < NJH; ++j) {
        acc[i + 4][j] = MFMA16(af[i * 2],     bfLo[j * 2],     acc[i + 4][j]);
        acc[i + 4][j] = MFMA16(af[i * 2 + 1], bfLo[j * 2 + 1], acc[i + 4][j]);
      }
    __builtin_amdgcn_s_setprio(0);
    __builtin_amdgcn_s_barrier();
  }

  // ---- epilogue
  #pragma unroll
  for (int j = 0; j < NJ; ++j) {
    const int col = n0 + wcn + j * 16 + lr;
    float bv = 0.f;
    if constexpr (EPI == 1) bv = bias[col];
    #pragma unroll
    for (int i = 0; i < 8; ++i) {
      #pragma unroll
      for (int r = 0; r < 4; ++r) {
        const int row = m0 + wrm + i * 16 + lg * 4 + r;
        float v = acc[i][j][r] + bv;
        if constexpr (EPI == 1) v = fmaxf(v, 0.f);
        if constexpr (sizeof(OutT) == 2) C[(size_t)row * N + col] = f2bf(v);
        else                             C[(size_t)row * N + col] = v;
      }
    }
  }
}

// ---------------------------------------------------------------- GEMM  C = A * Bw^T
// 128x128 tile, BK=32, double-buffered with counted vmcnt (round-8 verified).
template<int SK, int EPI, typename OutT>
__global__ __launch_bounds__(256) void gemm_bt(
    const short* __restrict__ A, const short* __restrict__ Bw,
    OutT* __restrict__ C0, OutT* __restrict__ C1, const float* __restrict__ bias,
    int M, int N, int K)
{
  __shared__ short Al[2][128 * 32];
  __shared__ short Bl[2][128 * 32];
  const int tid  = threadIdx.x;
  const int w    = tid >> 6, lane = tid & 63;
  const int ntiles = N >> 7;
  const int nwg = gridDim.x;
  const int bid = blockIdx.x;
  const int swz = (bid & 7) * (nwg >> 3) + (bid >> 3);
  const int tn = swz % ntiles, tm = swz / ntiles;
  const int m0 = tm << 7, n0 = tn << 7;
  const int wr = (w >> 1) << 6, wc = (w & 1) << 6;
  const int lr = lane & 15, lk = (lane >> 4) << 3;
  const int ra = lane >> 2, colA = (lane & 3) << 3;

  const int kper = K / SK;
  const int kbeg = (SK > 1) ? (int)blockIdx.y * kper : 0;
  const int T = kper >> 5;
  OutT* __restrict__ C = (SK > 1 && blockIdx.y) ? C1 : C0;

  const short* Ag0 = A  + (size_t)(m0 + w * 16 + ra) * K + colA;
  const short* Ag1 = A  + (size_t)(m0 + (w + 4) * 16 + ra) * K + colA;
  const short* Bg0 = Bw + (size_t)(n0 + w * 16 + ra) * K + colA;
  const short* Bg1 = Bw + (size_t)(n0 + (w + 4) * 16 + ra) * K + colA;

  f32x4 acc[4][4] = {};

  {
    const int k0 = kbeg;
    GLDS16(Ag0 + k0, &Al[0][w * 512]);
    GLDS16(Ag1 + k0, &Al[0][(w + 4) * 512]);
    GLDS16(Bg0 + k0, &Bl[0][w * 512]);
    GLDS16(Bg1 + k0, &Bl[0][(w + 4) * 512]);
  }

  for (int it = 0; it < T; ++it) {
    const int buf = it & 1;
    if (it + 1 < T) {
      const int k1 = kbeg + ((it + 1) << 5);
      GLDS16(Ag0 + k1, &Al[buf ^ 1][w * 512]);
      GLDS16(Ag1 + k1, &Al[buf ^ 1][(w + 4) * 512]);
      GLDS16(Bg0 + k1, &Bl[buf ^ 1][w * 512]);
      GLDS16(Bg1 + k1, &Bl[buf ^ 1][(w + 4) * 512]);
      asm volatile("s_waitcnt vmcnt(4)" ::: "memory");
    } else {
      asm volatile("s_waitcnt vmcnt(0)" ::: "memory");
    }
    __builtin_amdgcn_sched_barrier(0);
    __builtin_amdgcn_s_barrier();      // all waves' tile-it loads are in LDS

    bf16x8 af[4], bfr[4];
    #pragma unroll
    for (int i = 0; i < 4; ++i)
      af[i] = *(const bf16x8*)&Al[buf][(wr + i * 16 + lr) * 32 + lk];
    #pragma unroll
    for (int j = 0; j < 4; ++j)
      bfr[j] = *(const bf16x8*)&Bl[buf][(wc + j * 16 + lr) * 32 + lk];
    #pragma unroll
    for (int i = 0; i < 4; ++i)
      #pragma unroll
      for (int j = 0; j < 4; ++j)
        acc[i][j] = MFMA16(af[i], bfr[j], acc[i][j]);

    __builtin_amdgcn_s_barrier();      // readers done before iter it+1 overwrites buf
  }

  const int lg = lane >> 4;
  #pragma unroll
  for (int j = 0; j < 4; ++j) {
    const int col = n0 + wc + j * 16 + lr;
    float bv = 0.f;
    if constexpr (SK == 1 && EPI != 0) bv = bias[col];
    #pragma unroll
    for (int i = 0; i < 4; ++i) {
      #pragma unroll
      for (int r = 0; r < 4; ++r) {
        const int row = m0 + wr + i * 16 + lg * 4 + r;
        float v = acc[i][j][r] + bv;
        if constexpr (SK == 1 && EPI == 1) v = fmaxf(v, 0.f);
        if constexpr (sizeof(OutT) == 2) C[(size_t)row * N + col] = f2bf(v);
        else                             C[(size_t)row * N + col] = v;
      }
    }
  }
}

// ---------------------------------------------------------------- causal flash attention
// Round-12 verified: paired (p,31-p), 8 waves, K/V LDS double-buffer, 1 barrier/iter.
__global__ __launch_bounds__(512) void attn_kernel(
    const short* __restrict__ kqv, short* __restrict__ out)
{
  __shared__ short Kt[2][64][72];     // K rows (k) x d, double-buffered
  __shared__ short Vt[2][64][72];     // transposed: d x k, col k XOR-swizzled, dbuf
  __shared__ short Pl[8][16][72];     // per-wave P tile

  const int tid = threadIdx.x, w = tid >> 6, lane = tid & 63;
  const int wt = w & 3;               // wave index within its tile team
  const int p = blockIdx.x;           // 0..15, heaviest (p=0) dispatched first
  const int bh = blockIdx.y;          // 0..31
  const int b = bh >> 4, h = bh & 15;
  const int q0 = ((w < 4) ? (31 - p) : p) << 6;
  const int nkb = 32 - p;             // k-blocks for the hi tile (superset of lo's)
  const int lr = lane & 15, lg = lane >> 4;

  // Q fragment: rows q0 + wt*16 + lr, d = ks*32 + lg*8 ..+8; pre-scaled by 1/8 (exact)
  const size_t rowq = (size_t)(b * S_ + q0 + wt * 16 + lr) * 3072 + 1024 + h * 64;
  bf16x8 qf[2];
  qf[0] = *(const bf16x8*)&kqv[rowq + lg * 8];
  qf[1] = *(const bf16x8*)&kqv[rowq + 32 + lg * 8];
  #pragma unroll
  for (int ks = 0; ks < 2; ++ks)
    #pragma unroll
    for (int e = 0; e < 8; ++e)
      qf[ks][e] = f2bf(bf2f(qf[ks][e]) * 0.125f);

  f32x4 acc[4] = {};
  float m_run[4], l_run[4];
  #pragma unroll
  for (int r = 0; r < 4; ++r) { m_run[r] = -1e30f; l_run[r] = 0.f; }

  const int skk = tid >> 3;           // 0..63 staging row (k), one per 8 threads
  const int sc  = (tid & 7) << 3;     // staging col (d)
  const int vws = (tid & 7) << 3;     // V write swizzle: 8*((sc+e)>>3 & 7)
  const int vkc = skk ^ vws;          // V write column (swizzled)
  const short* gstage = kqv + (size_t)b * S_ * 3072 + h * 64 + sc;

  // prologue: tile 0 -> buf 0
  {
    bf16x8 kreg = *(const bf16x8*)&gstage[(size_t)skk * 3072];
    bf16x8 vreg = *(const bf16x8*)&gstage[(size_t)skk * 3072 + 2048];
    *(bf16x8*)&Kt[0][skk][sc] = kreg;
    #pragma unroll
    for (int e = 0; e < 8; ++e) Vt[0][sc + e][vkc] = vreg[e];
  }
  __syncthreads();

  for (int kbi = 0; kbi < nkb; ++kbi) {
    const int buf = kbi & 1;
    const int kb = kbi << 6;

    // ---- issue next tile's global loads (latency hides under process)
    bf16x8 kreg, vreg;
    const bool more = (kbi + 1 < nkb);
    if (more) {
      const size_t gb = (size_t)(((kbi + 1) << 6) + skk) * 3072;
      kreg = *(const bf16x8*)&gstage[gb];
      vreg = *(const bf16x8*)&gstage[gb + 2048];
    }

    // ---- per-wave processing on buf
    if (kb <= q0 + wt * 16 + 15) {
      f32x4 sacc[4] = {};
      __builtin_amdgcn_s_setprio(1);
      #pragma unroll
      for (int jt = 0; jt < 4; ++jt) {
        #pragma unroll
        for (int ks = 0; ks < 2; ++ks) {
          bf16x8 kf = *(const bf16x8*)&Kt[buf][jt * 16 + lr][ks * 32 + lg * 8];
          sacc[jt] = MFMA16(qf[ks], kf, sacc[jt]);
        }
      }
      __builtin_amdgcn_s_setprio(0);
      const bool full = (kb + 63 <= q0 + wt * 16);
      float rmax[4];
      if (full) {
        #pragma unroll
        for (int r = 0; r < 4; ++r)
          rmax[r] = fmaxf(fmaxf(sacc[0][r], sacc[1][r]), fmaxf(sacc[2][r], sacc[3][r]));
      } else {
        #pragma unroll
        for (int r = 0; r < 4; ++r) rmax[r] = -1e30f;
        #pragma unroll
        for (int jt = 0; jt < 4; ++jt) {
          const int kpos = kb + jt * 16 + lr;
          #pragma unroll
          for (int r = 0; r < 4; ++r) {
            const int qrow = q0 + wt * 16 + lg * 4 + r;
            float v = (kpos <= qrow) ? sacc[jt][r] : -1e30f;
            sacc[jt][r] = v;
            rmax[r] = fmaxf(rmax[r], v);
          }
        }
      }
      #pragma unroll
      for (int r = 0; r < 4; ++r) rmax[r] = dpp_max16(rmax[r]);
      int need = 0;
      #pragma unroll
      for (int r = 0; r < 4; ++r) need |= (rmax[r] > m_run[r] + 8.f) ? 1 : 0;
      if (__any(need)) {
        #pragma unroll
        for (int r = 0; r < 4; ++r) {
          const float mn = fmaxf(m_run[r], rmax[r]);
          const float al = exp2_hw((m_run[r] - mn) * LOG2E_);
          m_run[r] = mn;
          l_run[r] *= al;
          #pragma unroll
          for (int dt = 0; dt < 4; ++dt) acc[dt][r] *= al;
        }
      }
      float m2[4], rsum[4];
      #pragma unroll
      for (int r = 0; r < 4; ++r) { m2[r] = m_run[r] * LOG2E_; rsum[r] = 0.f; }
      #pragma unroll
      for (int jt = 0; jt < 4; ++jt)
        #pragma unroll
        for (int r = 0; r < 4; ++r) {
          const float pv = exp2_hw(__builtin_fmaf(sacc[jt][r], LOG2E_, -m2[r]));
          sacc[jt][r] = pv;
          rsum[r] += pv;
        }
      #pragma unroll
      for (int r = 0; r < 4; ++r) { rsum[r] = dpp_sum16(rsum[r]); l_run[r] += rsum[r]; }
      #pragma unroll
      for (int jt = 0; jt < 4; ++jt) {
        uint32_t w01, w23;
        asm("v_cvt_pk_bf16_f32 %0, %1, %2" : "=v"(w01) : "v"(sacc[jt][0]), "v"(sacc[jt][1]));
        asm("v_cvt_pk_bf16_f32 %0, %1, %2" : "=v"(w23) : "v"(sacc[jt][2]), "v"(sacc[jt][3]));
        Pl[w][lg * 4 + 0][jt * 16 + lr] = (short)(w01 & 0xffffu);
        Pl[w][lg * 4 + 1][jt * 16 + lr] = (short)(w01 >> 16);
        Pl[w][lg * 4 + 2][jt * 16 + lr] = (short)(w23 & 0xffffu);
        Pl[w][lg * 4 + 3][jt * 16 + lr] = (short)(w23 >> 16);
      }
      bf16x8 pa[2];
      pa[0] = *(const bf16x8*)&Pl[w][lr][lg * 8];
      pa[1] = *(const bf16x8*)&Pl[w][lr][32 + lg * 8];
      __builtin_amdgcn_s_setprio(1);
      #pragma unroll
      for (int dt = 0; dt < 4; ++dt) {
        const int vswz = (2 * dt + (lr >> 3)) << 3;
        #pragma unroll
        for (int ks = 0; ks < 2; ++ks) {
          bf16x8 vb = *(const bf16x8*)&Vt[buf][dt * 16 + lr][(ks * 32 + lg * 8) ^ vswz];
          acc[dt] = MFMA16(pa[ks], vb, acc[dt]);
        }
      }
      __builtin_amdgcn_s_setprio(0);
    }

    // ---- write prefetched tile into the other buffer
    if (more) {
      *(bf16x8*)&Kt[buf ^ 1][skk][sc] = kreg;
      #pragma unroll
      for (int e = 0; e < 8; ++e) Vt[buf ^ 1][sc + e][vkc] = vreg[e];
    }
    __syncthreads();   // orders: buf^1 writes before next read; buf reads before next write
  }

  // ---- epilogue: normalize and store (each wave owns unique rows)
  #pragma unroll
  for (int dt = 0; dt < 4; ++dt) {
    #pragma unroll
    for (int r = 0; r < 4; ++r) {
      const int d = h * 64 + dt * 16 + lr;
      const int q_row = q0 + wt * 16 + lg * 4 + r;
      out[(size_t)(b * S_ + q_row) * E_ + d] = f2bf(acc[dt][r] / l_run[r]);
    }
  }
}

// ---------------------------------------------------------------- residual + LayerNorm (split-K fold)
template<int FINAL>
__global__ __launch_bounds__(256) void ln_kernel(
    const float* __restrict__ y0, const float* __restrict__ y1,
    const float* __restrict__ bias, const void* __restrict__ res,
    const float* __restrict__ gam, const float* __restrict__ bet,
    void* __restrict__ outp)
{
  const int row = blockIdx.x, tid = threadIdx.x, lane = tid & 63, w = tid >> 6;
  float4 a = ((const float4*)(y0 + (size_t)row * E_))[tid];
  float4 c = ((const float4*)(y1 + (size_t)row * E_))[tid];
  float r[4] = {a.x + c.x, a.y + c.y, a.z + c.z, a.w + c.w};
  if constexpr (FINAL) {
    float4 bi = ((const float4*)bias)[tid];
    shortx4 rb = ((const shortx4*)((const short*)res + (size_t)row * E_))[tid];
    r[0] += bi.x + bf2f(rb.x); r[1] += bi.y + bf2f(rb.y);
    r[2] += bi.z + bf2f(rb.z); r[3] += bi.w + bf2f(rb.w);
  } else {
    float4 rv = ((const float4*)((const float*)res + (size_t)row * E_))[tid];
    r[0] += rv.x; r[1] += rv.y; r[2] += rv.z; r[3] += rv.w;
  }
  float s  = r[0] + r[1] + r[2] + r[3];
  float ss = r[0]*r[0] + r[1]*r[1] + r[2]*r[2] + r[3]*r[3];
  #pragma unroll
  for (int m = 32; m >= 1; m >>= 1) { s += __shfl_xor(s, m); ss += __shfl_xor(ss, m); }
  __shared__ float red[8];
  if (lane == 0) { red[w] = s; red[4 + w] = ss; }
  __syncthreads();
  s  = red[0] + red[1] + red[2] + red[3];
  ss = red[4] + red[5] + red[6] + red[7];
  const float mu  = s * (1.f / E_);
  const float var = ss * (1.f / E_) - mu * mu;
  const float rs  = rsqrtf(var + 1e-6f);
  float4 gv = ((const float4*)gam)[tid];
  float4 bv = ((const float4*)bet)[tid];
  float o0 = (r[0] - mu) * rs * gv.x + bv.x;
  float o1 = (r[1] - mu) * rs * gv.y + bv.y;
  float o2 = (r[2] - mu) * rs * gv.z + bv.z;
  float o3 = (r[3] - mu) * rs * gv.w + bv.w;
  if constexpr (FINAL) {
    float4 o; o.x = o0; o.y = o1; o.z = o2; o.w = o3;
    ((float4*)((float*)outp + (size_t)row * E_))[tid] = o;
  } else {
    shortx4 o; o.x = f2bf(o0); o.y = f2bf(o1); o.z = f2bf(o2); o.w = f2bf(o3);
    ((shortx4*)((short*)outp + (size_t)row * E_))[tid] = o;
  }
}

// ---------------------------------------------------------------- launch
// ws timeline (MB): [0-8 xb][8-14 wkqvb][14-16 wob][16-24 wupb][24-32 wdownb]
//   [32-56 kqv] -> attn [64-72 attno] -> proj [32-48 p0][48-64 p1] -> ln0 [72-80 xln]
//   -> up [32-64 hbuf] -> down [0-16 d0][80-96 d1] -> ln1.  Peak 96 MB.
extern "C" void kernel_launch(void* const* d_in, const int* in_sizes, int n_in,
                              void* d_out, int out_size, void* d_ws, size_t ws_size,
                              hipStream_t stream) {
  const float* x      = (const float*)d_in[0];
  const float* w_kqv  = (const float*)d_in[2];
  const float* w_o    = (const float*)d_in[3];
  const float* w_up   = (const float*)d_in[4];
  const float* b_up   = (const float*)d_in[5];
  const float* w_down = (const float*)d_in[6];
  const float* b_down = (const float*)d_in[7];
  const float* g1     = (const float*)d_in[8];
  const float* b1     = (const float*)d_in[9];
  const float* g2     = (const float*)d_in[10];
  const float* b2     = (const float*)d_in[11];
  float* out = (float*)d_out;

  char* ws = (char*)d_ws;
  short* xb     = (short*)(ws);
  short* wkqvb  = (short*)(ws + ((size_t)8  << 20));
  short* wob    = (short*)(ws + ((size_t)14 << 20));
  short* wupb   = (short*)(ws + ((size_t)16 << 20));
  short* wdownb = (short*)(ws + ((size_t)24 << 20));
  short* kqv    = (short*)(ws + ((size_t)32 << 20));
  float* proj0  = (float*)(ws + ((size_t)32 << 20));
  float* proj1  = (float*)(ws + ((size_t)48 << 20));
  short* hbuf   = (short*)(ws + ((size_t)32 << 20));
  short* attno  = (short*)(ws + ((size_t)64 << 20));
  short* xln    = (short*)(ws + ((size_t)72 << 20));
  float* down0  = (float*)(ws);
  float* down1  = (float*)(ws + ((size_t)80 << 20));

  cast_all<<<2048, 256, 0, stream>>>(x, w_kqv, w_o, w_up, w_down,
                                     xb, wkqvb, wob, wupb, wdownb);

  gemm_bt<1, 0, short><<<24 * 32, 256, 0, stream>>>(xb, wkqvb, kqv, nullptr, nullptr, M_, 3 * E_, E_);
  attn_kernel<<<dim3(16, B_ * H_), 512, 0, stream>>>(kqv, attno);
  gemm256_bt<128, 2, 0, float><<<dim3(128, 2), 512, 0, stream>>>(attno, wob, proj0, proj1, nullptr, M_, E_, E_);
  ln_kernel<0><<<M_, 256, 0, stream>>>(proj0, proj1, nullptr, x, g1, b1, xln);
  gemm256_bt<256, 1, 1, short><<<256, 512, 0, stream>>>(xln, wupb, hbuf, (short*)nullptr, b_up, M_, FF_, E_);
  gemm256_bt<128, 2, 0, float><<<dim3(128, 2), 512, 0, stream>>>(hbuf, wdownb, down0, down1, nullptr, M_, E_, FF_);
  ln_kernel<1><<<M_, 256, 0, stream>>>(down0, down1, b_down, xln, g2, b2, out);
}

// Round 16
// 232.956 us; speedup vs baseline: 1.0239x; 1.0239x over previous
//
#include <hip/hip_runtime.h>
#include <stdint.h>

#define B_ 2
#define S_ 2048
#define E_ 1024
#define H_ 16
#define HD_ 64
#define FF_ 4096
#define M_ 4096   // B*S
#define LOG2E_ 1.44269504f

typedef short bf16x8 __attribute__((ext_vector_type(8)));
typedef float f32x4  __attribute__((ext_vector_type(4)));
typedef short shortx4 __attribute__((ext_vector_type(4)));

#define MFMA16(a,b,c) __builtin_amdgcn_mfma_f32_16x16x32_bf16(a,b,c,0,0,0)

__device__ __forceinline__ short f2bf(float f) {
  uint32_t u = __builtin_bit_cast(uint32_t, f);
  u += 0x7fffu + ((u >> 16) & 1u);
  return (short)(u >> 16);
}
__device__ __forceinline__ float bf2f(short b) {
  uint32_t u = ((uint32_t)(uint16_t)b) << 16;
  return __builtin_bit_cast(float, u);
}
__device__ __forceinline__ float exp2_hw(float x) {
  float r;
  asm("v_exp_f32 %0, %1" : "=v"(r) : "v"(x));
  return r;
}

// DPP row-rotate (16-lane row), VALU-pipe cross-lane: ROW_ROR:N = 0x120|N
template<int CTRL>
__device__ __forceinline__ float dpp_ror(float x) {
  return __builtin_bit_cast(float,
    __builtin_amdgcn_update_dpp(0, __builtin_bit_cast(int, x), CTRL, 0xF, 0xF, true));
}
__device__ __forceinline__ float dpp_max16(float v) {
  v = fmaxf(v, dpp_ror<0x128>(v));
  v = fmaxf(v, dpp_ror<0x124>(v));
  v = fmaxf(v, dpp_ror<0x122>(v));
  v = fmaxf(v, dpp_ror<0x121>(v));
  return v;
}
__device__ __forceinline__ float dpp_sum16(float v) {
  v += dpp_ror<0x128>(v);
  v += dpp_ror<0x124>(v);
  v += dpp_ror<0x122>(v);
  v += dpp_ror<0x121>(v);
  return v;
}

// async global->LDS, 16B per lane, wave-uniform LDS base + lane*16 (per-lane global src)
#define GLDS16(g, l) __builtin_amdgcn_global_load_lds( \
    (const __attribute__((address_space(1))) unsigned int*)(g), \
    (__attribute__((address_space(3))) unsigned int*)(l), 16, 0, 0)

// ---------------------------------------------------------------- fused cast f32->bf16 (all 5 arrays)
__global__ void cast_all(const float* __restrict__ x, const float* __restrict__ wkqv,
                         const float* __restrict__ wo, const float* __restrict__ wup,
                         const float* __restrict__ wdown,
                         short* __restrict__ xb, short* __restrict__ wkqvb,
                         short* __restrict__ wob, short* __restrict__ wupb,
                         short* __restrict__ wdownb) {
  const int stride = gridDim.x * blockDim.x;
  for (int i = blockIdx.x * blockDim.x + threadIdx.x; i < 4194304; i += stride) {
    const int e = i << 2;
    const float* src; short* dst; int off;
    if (e < 4194304)       { src = x;     dst = xb;     off = e; }
    else if (e < 7340032)  { src = wkqv;  dst = wkqvb;  off = e - 4194304; }
    else if (e < 8388608)  { src = wo;    dst = wob;    off = e - 7340032; }
    else if (e < 12582912) { src = wup;   dst = wupb;   off = e - 8388608; }
    else                   { src = wdown; dst = wdownb; off = e - 12582912; }
    float4 v = *(const float4*)(src + off);
    shortx4 o;
    o.x = f2bf(v.x); o.y = f2bf(v.y); o.z = f2bf(v.z); o.w = f2bf(v.w);
    *(shortx4*)(dst + off) = o;
  }
}

// ---------------------------------------------------------------- GEMM 256xBN, BK=64, 8 waves
// Phase-structured (T2+T3+T4+T5), FULL-TILE prefetch: all of tile t+1's
// global_load_lds issued at phase a; vmcnt(TOT) waits only tile t's loads.
// XOR-swizzled LDS (phys 16B-slot = logical ^ (row&7), pre-swizzled source).
// BN in {256,128}. SK: split-K, blockIdx.y slice -> C0..C3. EPI=1: bias+relu.
template<int BN, int SK, int EPI, typename OutT>
__global__ __launch_bounds__(512, 2) void gemm256_bt(
    const short* __restrict__ A, const short* __restrict__ Bw,
    OutT* __restrict__ C0, OutT* __restrict__ C1,
    OutT* __restrict__ C2, OutT* __restrict__ C3,
    const float* __restrict__ bias,
    int M, int N, int K)
{
  constexpr int WCN  = BN / 4;       // per-wave N extent (64 or 32)
  constexpr int NJ   = WCN / 16;     // j-frags per wave (4 or 2)
  constexpr int NJH  = NJ / 2;       // j-frags per phase (2 or 1)
  constexpr int ISSB = BN / 64;      // B stage issues/thread (4 or 2)

  __shared__ short Al[2][256 * 64];
  __shared__ short Bl[2][BN * 64];
  const int tid = threadIdx.x;
  const int w = tid >> 6, lane = tid & 63;
  const int lr = lane & 15, lg = lane >> 4;
  const int ntiles = N / BN;
  const int nwg = gridDim.x;
  const int bid = blockIdx.x;
  const int swz = (bid & 7) * (nwg >> 3) + (bid >> 3);
  const int tn = swz % ntiles, tm = swz / ntiles;
  const int m0 = tm << 8, n0 = tn * BN;
  const int wrm = (w >> 2) << 7;       // 0 / 128
  const int wcn = (w & 3) * WCN;

  const int kper = K / SK;
  const int kbeg = (SK > 1) ? (int)blockIdx.y * kper : 0;
  const int T = kper >> 6;
  OutT* __restrict__ C = C0;
  if constexpr (SK > 1) {
    const int sl = blockIdx.y;
    C = (sl == 0) ? C0 : (sl == 1) ? C1 : (sl == 2) ? C2 : C3;
  }

  // staging: issue i stages chunk c = w + i*8 (8 rows x 128B, 64 lanes x 16B)
  const int srow = lane >> 3;
  const int scol = ((lane & 7) ^ srow) << 3;   // pre-swizzled source col (shorts)
  const short* Ag[4]; const short* Bg[ISSB];
  #pragma unroll
  for (int i = 0; i < 4; ++i)
    Ag[i] = A + (size_t)(m0 + (w + i * 8) * 8 + srow) * K + kbeg + scol;
  #pragma unroll
  for (int i = 0; i < ISSB; ++i)
    Bg[i] = Bw + (size_t)(n0 + (w + i * 8) * 8 + srow) * K + kbeg + scol;

  f32x4 acc[8][NJ] = {};

  // prologue: tile 0 -> buf 0
  #pragma unroll
  for (int i = 0; i < 4; ++i) GLDS16(Ag[i], &Al[0][(w + i * 8) * 512]);
  #pragma unroll
  for (int i = 0; i < ISSB; ++i) GLDS16(Bg[i], &Bl[0][(w + i * 8) * 512]);

  for (int t = 0; t < T; ++t) {
    const int buf = t & 1;
    const bool more = (t + 1 < T);
    const int k1 = (t + 1) << 6;

    bf16x8 af[8], bfLo[NJH * 2], bfHi[NJH * 2];
    const int ph0 = lg ^ (lr & 7);        // ks=0 swizzled slot
    const int ph1 = (4 + lg) ^ (lr & 7);  // ks=1

    // ---- phase a: issue ALL of t+1; vmcnt(TOT) drains tile t's loads
    if (more) {
      #pragma unroll
      for (int i = 0; i < 4; ++i) GLDS16(Ag[i] + k1, &Al[buf ^ 1][(w + i * 8) * 512]);
      #pragma unroll
      for (int i = 0; i < ISSB; ++i) GLDS16(Bg[i] + k1, &Bl[buf ^ 1][(w + i * 8) * 512]);
      if constexpr (ISSB == 4) asm volatile("s_waitcnt vmcnt(8)" ::: "memory");
      else                     asm volatile("s_waitcnt vmcnt(6)" ::: "memory");
    } else {
      asm volatile("s_waitcnt vmcnt(0)" ::: "memory");
    }
    __builtin_amdgcn_sched_barrier(0);
    __builtin_amdgcn_s_barrier();

    #pragma unroll
    for (int i = 0; i < 4; ++i) {
      const int R = wrm + i * 16 + lr;
      af[i * 2]     = *(const bf16x8*)&Al[buf][R * 64 + ph0 * 8];
      af[i * 2 + 1] = *(const bf16x8*)&Al[buf][R * 64 + ph1 * 8];
    }
    #pragma unroll
    for (int j = 0; j < NJH; ++j) {
      const int R = wcn + j * 16 + lr;
      bfLo[j * 2]     = *(const bf16x8*)&Bl[buf][R * 64 + ph0 * 8];
      bfLo[j * 2 + 1] = *(const bf16x8*)&Bl[buf][R * 64 + ph1 * 8];
    }
    __builtin_amdgcn_s_setprio(1);
    #pragma unroll
    for (int i = 0; i < 4; ++i)
      #pragma unroll
      for (int j = 0; j < NJH; ++j) {
        acc[i][j] = MFMA16(af[i * 2],     bfLo[j * 2],     acc[i][j]);
        acc[i][j] = MFMA16(af[i * 2 + 1], bfLo[j * 2 + 1], acc[i][j]);
      }
    __builtin_amdgcn_s_setprio(0);
    __builtin_amdgcn_s_barrier();

    // ---- phase b: reads B j-hi; MFMA i0-3 x j-hi
    #pragma unroll
    for (int j = 0; j < NJH; ++j) {
      const int R = wcn + (j + NJH) * 16 + lr;
      bfHi[j * 2]     = *(const bf16x8*)&Bl[buf][R * 64 + ph0 * 8];
      bfHi[j * 2 + 1] = *(const bf16x8*)&Bl[buf][R * 64 + ph1 * 8];
    }
    __builtin_amdgcn_s_setprio(1);
    #pragma unroll
    for (int i = 0; i < 4; ++i)
      #pragma unroll
      for (int j = 0; j < NJH; ++j) {
        acc[i][j + NJH] = MFMA16(af[i * 2],     bfHi[j * 2],     acc[i][j + NJH]);
        acc[i][j + NJH] = MFMA16(af[i * 2 + 1], bfHi[j * 2 + 1], acc[i][j + NJH]);
      }
    __builtin_amdgcn_s_setprio(0);
    __builtin_amdgcn_s_barrier();

    // ---- phase c: reads A i4-7; MFMA i4-7 x j-hi
    #pragma unroll
    for (int i = 0; i < 4; ++i) {
      const int R = wrm + (i + 4) * 16 + lr;
      af[i * 2]     = *(const bf16x8*)&Al[buf][R * 64 + ph0 * 8];
      af[i * 2 + 1] = *(const bf16x8*)&Al[buf][R * 64 + ph1 * 8];
    }
    __builtin_amdgcn_s_setprio(1);
    #pragma unroll
    for (int i = 0; i < 4; ++i)
      #pragma unroll
      for (int j = 0; j < NJH; ++j) {
        acc[i + 4][j + NJH] = MFMA16(af[i * 2],     bfHi[j * 2],     acc[i + 4][j + NJH]);
        acc[i + 4][j + NJH] = MFMA16(af[i * 2 + 1], bfHi[j * 2 + 1], acc[i + 4][j + NJH]);
      }
    __builtin_amdgcn_s_setprio(0);
    __builtin_amdgcn_s_barrier();

    // ---- phase d: MFMA i4-7 x j-lo (bfLo still live)
    __builtin_amdgcn_s_setprio(1);
    #pragma unroll
    for (int i = 0; i < 4; ++i)
      #pragma unroll
      for (int j = 0; j < NJH; ++j) {
        acc[i + 4][j] = MFMA16(af[i * 2],     bfLo[j * 2],     acc[i + 4][j]);
        acc[i + 4][j] = MFMA16(af[i * 2 + 1], bfLo[j * 2 + 1], acc[i + 4][j]);
      }
    __builtin_amdgcn_s_setprio(0);
    __builtin_amdgcn_s_barrier();
  }

  // ---- epilogue
  #pragma unroll
  for (int j = 0; j < NJ; ++j) {
    const int col = n0 + wcn + j * 16 + lr;
    float bv = 0.f;
    if constexpr (EPI == 1) bv = bias[col];
    #pragma unroll
    for (int i = 0; i < 8; ++i) {
      #pragma unroll
      for (int r = 0; r < 4; ++r) {
        const int row = m0 + wrm + i * 16 + lg * 4 + r;
        float v = acc[i][j][r] + bv;
        if constexpr (EPI == 1) v = fmaxf(v, 0.f);
        if constexpr (sizeof(OutT) == 2) C[(size_t)row * N + col] = f2bf(v);
        else                             C[(size_t)row * N + col] = v;
      }
    }
  }
}

// ---------------------------------------------------------------- GEMM  C = A * Bw^T
// 128x128 tile, BK=32, double-buffered with counted vmcnt (round-8 verified).
template<int SK, int EPI, typename OutT>
__global__ __launch_bounds__(256) void gemm_bt(
    const short* __restrict__ A, const short* __restrict__ Bw,
    OutT* __restrict__ C0, OutT* __restrict__ C1, const float* __restrict__ bias,
    int M, int N, int K)
{
  __shared__ short Al[2][128 * 32];
  __shared__ short Bl[2][128 * 32];
  const int tid  = threadIdx.x;
  const int w    = tid >> 6, lane = tid & 63;
  const int ntiles = N >> 7;
  const int nwg = gridDim.x;
  const int bid = blockIdx.x;
  const int swz = (bid & 7) * (nwg >> 3) + (bid >> 3);
  const int tn = swz % ntiles, tm = swz / ntiles;
  const int m0 = tm << 7, n0 = tn << 7;
  const int wr = (w >> 1) << 6, wc = (w & 1) << 6;
  const int lr = lane & 15, lk = (lane >> 4) << 3;
  const int ra = lane >> 2, colA = (lane & 3) << 3;

  const int kper = K / SK;
  const int kbeg = (SK > 1) ? (int)blockIdx.y * kper : 0;
  const int T = kper >> 5;
  OutT* __restrict__ C = (SK > 1 && blockIdx.y) ? C1 : C0;

  const short* Ag0 = A  + (size_t)(m0 + w * 16 + ra) * K + colA;
  const short* Ag1 = A  + (size_t)(m0 + (w + 4) * 16 + ra) * K + colA;
  const short* Bg0 = Bw + (size_t)(n0 + w * 16 + ra) * K + colA;
  const short* Bg1 = Bw + (size_t)(n0 + (w + 4) * 16 + ra) * K + colA;

  f32x4 acc[4][4] = {};

  {
    const int k0 = kbeg;
    GLDS16(Ag0 + k0, &Al[0][w * 512]);
    GLDS16(Ag1 + k0, &Al[0][(w + 4) * 512]);
    GLDS16(Bg0 + k0, &Bl[0][w * 512]);
    GLDS16(Bg1 + k0, &Bl[0][(w + 4) * 512]);
  }

  for (int it = 0; it < T; ++it) {
    const int buf = it & 1;
    if (it + 1 < T) {
      const int k1 = kbeg + ((it + 1) << 5);
      GLDS16(Ag0 + k1, &Al[buf ^ 1][w * 512]);
      GLDS16(Ag1 + k1, &Al[buf ^ 1][(w + 4) * 512]);
      GLDS16(Bg0 + k1, &Bl[buf ^ 1][w * 512]);
      GLDS16(Bg1 + k1, &Bl[buf ^ 1][(w + 4) * 512]);
      asm volatile("s_waitcnt vmcnt(4)" ::: "memory");
    } else {
      asm volatile("s_waitcnt vmcnt(0)" ::: "memory");
    }
    __builtin_amdgcn_sched_barrier(0);
    __builtin_amdgcn_s_barrier();      // all waves' tile-it loads are in LDS

    bf16x8 af[4], bfr[4];
    #pragma unroll
    for (int i = 0; i < 4; ++i)
      af[i] = *(const bf16x8*)&Al[buf][(wr + i * 16 + lr) * 32 + lk];
    #pragma unroll
    for (int j = 0; j < 4; ++j)
      bfr[j] = *(const bf16x8*)&Bl[buf][(wc + j * 16 + lr) * 32 + lk];
    #pragma unroll
    for (int i = 0; i < 4; ++i)
      #pragma unroll
      for (int j = 0; j < 4; ++j)
        acc[i][j] = MFMA16(af[i], bfr[j], acc[i][j]);

    __builtin_amdgcn_s_barrier();      // readers done before iter it+1 overwrites buf
  }

  const int lg = lane >> 4;
  #pragma unroll
  for (int j = 0; j < 4; ++j) {
    const int col = n0 + wc + j * 16 + lr;
    float bv = 0.f;
    if constexpr (SK == 1 && EPI != 0) bv = bias[col];
    #pragma unroll
    for (int i = 0; i < 4; ++i) {
      #pragma unroll
      for (int r = 0; r < 4; ++r) {
        const int row = m0 + wr + i * 16 + lg * 4 + r;
        float v = acc[i][j][r] + bv;
        if constexpr (SK == 1 && EPI == 1) v = fmaxf(v, 0.f);
        if constexpr (sizeof(OutT) == 2) C[(size_t)row * N + col] = f2bf(v);
        else                             C[(size_t)row * N + col] = v;
      }
    }
  }
}

// ---------------------------------------------------------------- causal flash attention
// Round-12 verified: paired (p,31-p), 8 waves, K/V LDS double-buffer, 1 barrier/iter.
__global__ __launch_bounds__(512) void attn_kernel(
    const short* __restrict__ kqv, short* __restrict__ out)
{
  __shared__ short Kt[2][64][72];     // K rows (k) x d, double-buffered
  __shared__ short Vt[2][64][72];     // transposed: d x k, col k XOR-swizzled, dbuf
  __shared__ short Pl[8][16][72];     // per-wave P tile

  const int tid = threadIdx.x, w = tid >> 6, lane = tid & 63;
  const int wt = w & 3;               // wave index within its tile team
  const int p = blockIdx.x;           // 0..15, heaviest (p=0) dispatched first
  const int bh = blockIdx.y;          // 0..31
  const int b = bh >> 4, h = bh & 15;
  const int q0 = ((w < 4) ? (31 - p) : p) << 6;
  const int nkb = 32 - p;             // k-blocks for the hi tile (superset of lo's)
  const int lr = lane & 15, lg = lane >> 4;

  // Q fragment: rows q0 + wt*16 + lr, d = ks*32 + lg*8 ..+8; pre-scaled by 1/8 (exact)
  const size_t rowq = (size_t)(b * S_ + q0 + wt * 16 + lr) * 3072 + 1024 + h * 64;
  bf16x8 qf[2];
  qf[0] = *(const bf16x8*)&kqv[rowq + lg * 8];
  qf[1] = *(const bf16x8*)&kqv[rowq + 32 + lg * 8];
  #pragma unroll
  for (int ks = 0; ks < 2; ++ks)
    #pragma unroll
    for (int e = 0; e < 8; ++e)
      qf[ks][e] = f2bf(bf2f(qf[ks][e]) * 0.125f);

  f32x4 acc[4] = {};
  float m_run[4], l_run[4];
  #pragma unroll
  for (int r = 0; r < 4; ++r) { m_run[r] = -1e30f; l_run[r] = 0.f; }

  const int skk = tid >> 3;           // 0..63 staging row (k), one per 8 threads
  const int sc  = (tid & 7) << 3;     // staging col (d)
  const int vws = (tid & 7) << 3;     // V write swizzle: 8*((sc+e)>>3 & 7)
  const int vkc = skk ^ vws;          // V write column (swizzled)
  const short* gstage = kqv + (size_t)b * S_ * 3072 + h * 64 + sc;

  // prologue: tile 0 -> buf 0
  {
    bf16x8 kreg = *(const bf16x8*)&gstage[(size_t)skk * 3072];
    bf16x8 vreg = *(const bf16x8*)&gstage[(size_t)skk * 3072 + 2048];
    *(bf16x8*)&Kt[0][skk][sc] = kreg;
    #pragma unroll
    for (int e = 0; e < 8; ++e) Vt[0][sc + e][vkc] = vreg[e];
  }
  __syncthreads();

  for (int kbi = 0; kbi < nkb; ++kbi) {
    const int buf = kbi & 1;
    const int kb = kbi << 6;

    // ---- issue next tile's global loads (latency hides under process)
    bf16x8 kreg, vreg;
    const bool more = (kbi + 1 < nkb);
    if (more) {
      const size_t gb = (size_t)(((kbi + 1) << 6) + skk) * 3072;
      kreg = *(const bf16x8*)&gstage[gb];
      vreg = *(const bf16x8*)&gstage[gb + 2048];
    }

    // ---- per-wave processing on buf
    if (kb <= q0 + wt * 16 + 15) {
      f32x4 sacc[4] = {};
      __builtin_amdgcn_s_setprio(1);
      #pragma unroll
      for (int jt = 0; jt < 4; ++jt) {
        #pragma unroll
        for (int ks = 0; ks < 2; ++ks) {
          bf16x8 kf = *(const bf16x8*)&Kt[buf][jt * 16 + lr][ks * 32 + lg * 8];
          sacc[jt] = MFMA16(qf[ks], kf, sacc[jt]);
        }
      }
      __builtin_amdgcn_s_setprio(0);
      const bool full = (kb + 63 <= q0 + wt * 16);
      float rmax[4];
      if (full) {
        #pragma unroll
        for (int r = 0; r < 4; ++r)
          rmax[r] = fmaxf(fmaxf(sacc[0][r], sacc[1][r]), fmaxf(sacc[2][r], sacc[3][r]));
      } else {
        #pragma unroll
        for (int r = 0; r < 4; ++r) rmax[r] = -1e30f;
        #pragma unroll
        for (int jt = 0; jt < 4; ++jt) {
          const int kpos = kb + jt * 16 + lr;
          #pragma unroll
          for (int r = 0; r < 4; ++r) {
            const int qrow = q0 + wt * 16 + lg * 4 + r;
            float v = (kpos <= qrow) ? sacc[jt][r] : -1e30f;
            sacc[jt][r] = v;
            rmax[r] = fmaxf(rmax[r], v);
          }
        }
      }
      #pragma unroll
      for (int r = 0; r < 4; ++r) rmax[r] = dpp_max16(rmax[r]);
      int need = 0;
      #pragma unroll
      for (int r = 0; r < 4; ++r) need |= (rmax[r] > m_run[r] + 8.f) ? 1 : 0;
      if (__any(need)) {
        #pragma unroll
        for (int r = 0; r < 4; ++r) {
          const float mn = fmaxf(m_run[r], rmax[r]);
          const float al = exp2_hw((m_run[r] - mn) * LOG2E_);
          m_run[r] = mn;
          l_run[r] *= al;
          #pragma unroll
          for (int dt = 0; dt < 4; ++dt) acc[dt][r] *= al;
        }
      }
      float m2[4], rsum[4];
      #pragma unroll
      for (int r = 0; r < 4; ++r) { m2[r] = m_run[r] * LOG2E_; rsum[r] = 0.f; }
      #pragma unroll
      for (int jt = 0; jt < 4; ++jt)
        #pragma unroll
        for (int r = 0; r < 4; ++r) {
          const float pv = exp2_hw(__builtin_fmaf(sacc[jt][r], LOG2E_, -m2[r]));
          sacc[jt][r] = pv;
          rsum[r] += pv;
        }
      #pragma unroll
      for (int r = 0; r < 4; ++r) { rsum[r] = dpp_sum16(rsum[r]); l_run[r] += rsum[r]; }
      #pragma unroll
      for (int jt = 0; jt < 4; ++jt) {
        uint32_t w01, w23;
        asm("v_cvt_pk_bf16_f32 %0, %1, %2" : "=v"(w01) : "v"(sacc[jt][0]), "v"(sacc[jt][1]));
        asm("v_cvt_pk_bf16_f32 %0, %1, %2" : "=v"(w23) : "v"(sacc[jt][2]), "v"(sacc[jt][3]));
        Pl[w][lg * 4 + 0][jt * 16 + lr] = (short)(w01 & 0xffffu);
        Pl[w][lg * 4 + 1][jt * 16 + lr] = (short)(w01 >> 16);
        Pl[w][lg * 4 + 2][jt * 16 + lr] = (short)(w23 & 0xffffu);
        Pl[w][lg * 4 + 3][jt * 16 + lr] = (short)(w23 >> 16);
      }
      bf16x8 pa[2];
      pa[0] = *(const bf16x8*)&Pl[w][lr][lg * 8];
      pa[1] = *(const bf16x8*)&Pl[w][lr][32 + lg * 8];
      __builtin_amdgcn_s_setprio(1);
      #pragma unroll
      for (int dt = 0; dt < 4; ++dt) {
        const int vswz = (2 * dt + (lr >> 3)) << 3;
        #pragma unroll
        for (int ks = 0; ks < 2; ++ks) {
          bf16x8 vb = *(const bf16x8*)&Vt[buf][dt * 16 + lr][(ks * 32 + lg * 8) ^ vswz];
          acc[dt] = MFMA16(pa[ks], vb, acc[dt]);
        }
      }
      __builtin_amdgcn_s_setprio(0);
    }

    // ---- write prefetched tile into the other buffer
    if (more) {
      *(bf16x8*)&Kt[buf ^ 1][skk][sc] = kreg;
      #pragma unroll
      for (int e = 0; e < 8; ++e) Vt[buf ^ 1][sc + e][vkc] = vreg[e];
    }
    __syncthreads();   // orders: buf^1 writes before next read; buf reads before next write
  }

  // ---- epilogue: normalize and store (each wave owns unique rows)
  #pragma unroll
  for (int dt = 0; dt < 4; ++dt) {
    #pragma unroll
    for (int r = 0; r < 4; ++r) {
      const int d = h * 64 + dt * 16 + lr;
      const int q_row = q0 + wt * 16 + lg * 4 + r;
      out[(size_t)(b * S_ + q_row) * E_ + d] = f2bf(acc[dt][r] / l_run[r]);
    }
  }
}

// ---------------------------------------------------------------- residual + LayerNorm (2x f32 fold, proj)
template<int FINAL>
__global__ __launch_bounds__(256) void ln_kernel(
    const float* __restrict__ y0, const float* __restrict__ y1,
    const float* __restrict__ bias, const void* __restrict__ res,
    const float* __restrict__ gam, const float* __restrict__ bet,
    void* __restrict__ outp)
{
  const int row = blockIdx.x, tid = threadIdx.x, lane = tid & 63, w = tid >> 6;
  float4 a = ((const float4*)(y0 + (size_t)row * E_))[tid];
  float4 c = ((const float4*)(y1 + (size_t)row * E_))[tid];
  float r[4] = {a.x + c.x, a.y + c.y, a.z + c.z, a.w + c.w};
  if constexpr (FINAL) {
    float4 bi = ((const float4*)bias)[tid];
    shortx4 rb = ((const shortx4*)((const short*)res + (size_t)row * E_))[tid];
    r[0] += bi.x + bf2f(rb.x); r[1] += bi.y + bf2f(rb.y);
    r[2] += bi.z + bf2f(rb.z); r[3] += bi.w + bf2f(rb.w);
  } else {
    float4 rv = ((const float4*)((const float*)res + (size_t)row * E_))[tid];
    r[0] += rv.x; r[1] += rv.y; r[2] += rv.z; r[3] += rv.w;
  }
  float s  = r[0] + r[1] + r[2] + r[3];
  float ss = r[0]*r[0] + r[1]*r[1] + r[2]*r[2] + r[3]*r[3];
  #pragma unroll
  for (int m = 32; m >= 1; m >>= 1) { s += __shfl_xor(s, m); ss += __shfl_xor(ss, m); }
  __shared__ float red[8];
  if (lane == 0) { red[w] = s; red[4 + w] = ss; }
  __syncthreads();
  s  = red[0] + red[1] + red[2] + red[3];
  ss = red[4] + red[5] + red[6] + red[7];
  const float mu  = s * (1.f / E_);
  const float var = ss * (1.f / E_) - mu * mu;
  const float rs  = rsqrtf(var + 1e-6f);
  float4 gv = ((const float4*)gam)[tid];
  float4 bv = ((const float4*)bet)[tid];
  float o0 = (r[0] - mu) * rs * gv.x + bv.x;
  float o1 = (r[1] - mu) * rs * gv.y + bv.y;
  float o2 = (r[2] - mu) * rs * gv.z + bv.z;
  float o3 = (r[3] - mu) * rs * gv.w + bv.w;
  if constexpr (FINAL) {
    float4 o; o.x = o0; o.y = o1; o.z = o2; o.w = o3;
    ((float4*)((float*)outp + (size_t)row * E_))[tid] = o;
  } else {
    shortx4 o; o.x = f2bf(o0); o.y = f2bf(o1); o.z = f2bf(o2); o.w = f2bf(o3);
    ((shortx4*)((short*)outp + (size_t)row * E_))[tid] = o;
  }
}

// ---------------------------------------------------------------- final LN: fold 4 bf16 partials + bias + bf16 residual -> f32
__global__ __launch_bounds__(256) void ln_fold4(
    const short* __restrict__ y0, const short* __restrict__ y1,
    const short* __restrict__ y2, const short* __restrict__ y3,
    const float* __restrict__ bias, const short* __restrict__ res,
    const float* __restrict__ gam, const float* __restrict__ bet,
    float* __restrict__ outp)
{
  const int row = blockIdx.x, tid = threadIdx.x, lane = tid & 63, w = tid >> 6;
  const size_t base = (size_t)row * E_;
  shortx4 a0 = ((const shortx4*)(y0 + base))[tid];
  shortx4 a1 = ((const shortx4*)(y1 + base))[tid];
  shortx4 a2 = ((const shortx4*)(y2 + base))[tid];
  shortx4 a3 = ((const shortx4*)(y3 + base))[tid];
  shortx4 rb = ((const shortx4*)(res + base))[tid];
  float4 bi = ((const float4*)bias)[tid];
  float r[4];
  #pragma unroll
  for (int j = 0; j < 4; ++j)
    r[j] = bf2f(a0[j]) + bf2f(a1[j]) + bf2f(a2[j]) + bf2f(a3[j]) + bf2f(rb[j]);
  r[0] += bi.x; r[1] += bi.y; r[2] += bi.z; r[3] += bi.w;
  float s  = r[0] + r[1] + r[2] + r[3];
  float ss = r[0]*r[0] + r[1]*r[1] + r[2]*r[2] + r[3]*r[3];
  #pragma unroll
  for (int m = 32; m >= 1; m >>= 1) { s += __shfl_xor(s, m); ss += __shfl_xor(ss, m); }
  __shared__ float red[8];
  if (lane == 0) { red[w] = s; red[4 + w] = ss; }
  __syncthreads();
  s  = red[0] + red[1] + red[2] + red[3];
  ss = red[4] + red[5] + red[6] + red[7];
  const float mu  = s * (1.f / E_);
  const float var = ss * (1.f / E_) - mu * mu;
  const float rs  = rsqrtf(var + 1e-6f);
  float4 gv = ((const float4*)gam)[tid];
  float4 bv = ((const float4*)bet)[tid];
  float4 o;
  o.x = (r[0] - mu) * rs * gv.x + bv.x;
  o.y = (r[1] - mu) * rs * gv.y + bv.y;
  o.z = (r[2] - mu) * rs * gv.z + bv.z;
  o.w = (r[3] - mu) * rs * gv.w + bv.w;
  ((float4*)(outp + base))[tid] = o;
}

// ---------------------------------------------------------------- launch
// ws timeline (MB): [0-8 xb][8-14 wkqvb][14-16 wob][16-24 wupb][24-32 wdownb]
//   [32-56 kqv] -> attn [64-72 attno] -> proj [32-48 p0][48-64 p1] -> ln0 [72-80 xln]
//   -> up [32-64 hbuf] -> down (bf16 partials) [0-8 d0][8-16 d1][16-24 d2][64-72 d3]
//   -> ln_fold4.  Peak 96 MB.
extern "C" void kernel_launch(void* const* d_in, const int* in_sizes, int n_in,
                              void* d_out, int out_size, void* d_ws, size_t ws_size,
                              hipStream_t stream) {
  const float* x      = (const float*)d_in[0];
  const float* w_kqv  = (const float*)d_in[2];
  const float* w_o    = (const float*)d_in[3];
  const float* w_up   = (const float*)d_in[4];
  const float* b_up   = (const float*)d_in[5];
  const float* w_down = (const float*)d_in[6];
  const float* b_down = (const float*)d_in[7];
  const float* g1     = (const float*)d_in[8];
  const float* b1     = (const float*)d_in[9];
  const float* g2     = (const float*)d_in[10];
  const float* b2     = (const float*)d_in[11];
  float* out = (float*)d_out;

  char* ws = (char*)d_ws;
  short* xb     = (short*)(ws);
  short* wkqvb  = (short*)(ws + ((size_t)8  << 20));
  short* wob    = (short*)(ws + ((size_t)14 << 20));
  short* wupb   = (short*)(ws + ((size_t)16 << 20));
  short* wdownb = (short*)(ws + ((size_t)24 << 20));
  short* kqv    = (short*)(ws + ((size_t)32 << 20));
  float* proj0  = (float*)(ws + ((size_t)32 << 20));
  float* proj1  = (float*)(ws + ((size_t)48 << 20));
  short* hbuf   = (short*)(ws + ((size_t)32 << 20));
  short* attno  = (short*)(ws + ((size_t)64 << 20));
  short* xln    = (short*)(ws + ((size_t)72 << 20));
  short* dwn0   = (short*)(ws);                         // 0-8   (xb dead)
  short* dwn1   = (short*)(ws + ((size_t)8  << 20));    // 8-16  (wkqvb/wob dead)
  short* dwn2   = (short*)(ws + ((size_t)16 << 20));    // 16-24 (wupb dead)
  short* dwn3   = (short*)(ws + ((size_t)64 << 20));    // 64-72 (attno dead)

  cast_all<<<2048, 256, 0, stream>>>(x, w_kqv, w_o, w_up, w_down,
                                     xb, wkqvb, wob, wupb, wdownb);

  gemm_bt<1, 0, short><<<24 * 32, 256, 0, stream>>>(xb, wkqvb, kqv, nullptr, nullptr, M_, 3 * E_, E_);
  attn_kernel<<<dim3(16, B_ * H_), 512, 0, stream>>>(kqv, attno);
  gemm256_bt<128, 2, 0, float><<<dim3(128, 2), 512, 0, stream>>>(
      attno, wob, proj0, proj1, nullptr, nullptr, nullptr, M_, E_, E_);
  ln_kernel<0><<<M_, 256, 0, stream>>>(proj0, proj1, nullptr, x, g1, b1, xln);
  gemm256_bt<256, 1, 1, short><<<256, 512, 0, stream>>>(
      xln, wupb, hbuf, nullptr, nullptr, nullptr, b_up, M_, FF_, E_);
  gemm256_bt<256, 4, 0, short><<<dim3(64, 4), 512, 0, stream>>>(
      hbuf, wdownb, dwn0, dwn1, dwn2, dwn3, nullptr, M_, E_, FF_);
  ln_fold4<<<M_, 256, 0, stream>>>(dwn0, dwn1, dwn2, dwn3, b_down, xln, g2, b2, out);
}

// Round 17
// 228.958 us; speedup vs baseline: 1.0418x; 1.0175x over previous
//
#include <hip/hip_runtime.h>
#include <stdint.h>

#define B_ 2
#define S_ 2048
#define E_ 1024
#define H_ 16
#define HD_ 64
#define FF_ 4096
#define M_ 4096   // B*S
#define LOG2E_ 1.44269504f

typedef short bf16x8 __attribute__((ext_vector_type(8)));
typedef float f32x4  __attribute__((ext_vector_type(4)));
typedef short shortx4 __attribute__((ext_vector_type(4)));

#define MFMA16(a,b,c) __builtin_amdgcn_mfma_f32_16x16x32_bf16(a,b,c,0,0,0)

__device__ __forceinline__ short f2bf(float f) {
  uint32_t u = __builtin_bit_cast(uint32_t, f);
  u += 0x7fffu + ((u >> 16) & 1u);
  return (short)(u >> 16);
}
__device__ __forceinline__ float bf2f(short b) {
  uint32_t u = ((uint32_t)(uint16_t)b) << 16;
  return __builtin_bit_cast(float, u);
}
__device__ __forceinline__ float exp2_hw(float x) {
  float r;
  asm("v_exp_f32 %0, %1" : "=v"(r) : "v"(x));
  return r;
}

// DPP row-rotate (16-lane row), VALU-pipe cross-lane: ROW_ROR:N = 0x120|N
template<int CTRL>
__device__ __forceinline__ float dpp_ror(float x) {
  return __builtin_bit_cast(float,
    __builtin_amdgcn_update_dpp(0, __builtin_bit_cast(int, x), CTRL, 0xF, 0xF, true));
}
__device__ __forceinline__ float dpp_max16(float v) {
  v = fmaxf(v, dpp_ror<0x128>(v));
  v = fmaxf(v, dpp_ror<0x124>(v));
  v = fmaxf(v, dpp_ror<0x122>(v));
  v = fmaxf(v, dpp_ror<0x121>(v));
  return v;
}
__device__ __forceinline__ float dpp_sum16(float v) {
  v += dpp_ror<0x128>(v);
  v += dpp_ror<0x124>(v);
  v += dpp_ror<0x122>(v);
  v += dpp_ror<0x121>(v);
  return v;
}

// async global->LDS, 16B per lane, wave-uniform LDS base + lane*16 (per-lane global src)
#define GLDS16(g, l) __builtin_amdgcn_global_load_lds( \
    (const __attribute__((address_space(1))) unsigned int*)(g), \
    (__attribute__((address_space(3))) unsigned int*)(l), 16, 0, 0)

// ---------------------------------------------------------------- fused cast f32->bf16 (all 5 arrays)
__global__ void cast_all(const float* __restrict__ x, const float* __restrict__ wkqv,
                         const float* __restrict__ wo, const float* __restrict__ wup,
                         const float* __restrict__ wdown,
                         short* __restrict__ xb, short* __restrict__ wkqvb,
                         short* __restrict__ wob, short* __restrict__ wupb,
                         short* __restrict__ wdownb) {
  const int stride = gridDim.x * blockDim.x;
  for (int i = blockIdx.x * blockDim.x + threadIdx.x; i < 4194304; i += stride) {
    const int e = i << 2;
    const float* src; short* dst; int off;
    if (e < 4194304)       { src = x;     dst = xb;     off = e; }
    else if (e < 7340032)  { src = wkqv;  dst = wkqvb;  off = e - 4194304; }
    else if (e < 8388608)  { src = wo;    dst = wob;    off = e - 7340032; }
    else if (e < 12582912) { src = wup;   dst = wupb;   off = e - 8388608; }
    else                   { src = wdown; dst = wdownb; off = e - 12582912; }
    float4 v = *(const float4*)(src + off);
    shortx4 o;
    o.x = f2bf(v.x); o.y = f2bf(v.y); o.z = f2bf(v.z); o.w = f2bf(v.w);
    *(shortx4*)(dst + off) = o;
  }
}

// ---------------------------------------------------------------- GEMM 256xBN, BK=64, 8 waves
// Phase-structured (T2+T3+T4+T5), FULL-TILE prefetch. Inner phase barriers
// REMOVED (round-17): within a tile all waves only READ buf; staging targets
// buf^1 gated by next tile's vmcnt+barrier; WAR on buf covered by the
// end-of-tile barrier. 2 barriers/tile total; compiler free to interleave
// ds_read with MFMA across the whole tile.
template<int BN, int SK, int EPI, typename OutT>
__global__ __launch_bounds__(512, 2) void gemm256_bt(
    const short* __restrict__ A, const short* __restrict__ Bw,
    OutT* __restrict__ C0, OutT* __restrict__ C1,
    OutT* __restrict__ C2, OutT* __restrict__ C3,
    const float* __restrict__ bias,
    int M, int N, int K)
{
  constexpr int WCN  = BN / 4;       // per-wave N extent (64 or 32)
  constexpr int NJ   = WCN / 16;     // j-frags per wave (4 or 2)
  constexpr int NJH  = NJ / 2;       // j-frags per phase (2 or 1)
  constexpr int ISSB = BN / 64;      // B stage issues/thread (4 or 2)

  __shared__ short Al[2][256 * 64];
  __shared__ short Bl[2][BN * 64];
  const int tid = threadIdx.x;
  const int w = tid >> 6, lane = tid & 63;
  const int lr = lane & 15, lg = lane >> 4;
  const int ntiles = N / BN;
  const int nwg = gridDim.x;
  const int bid = blockIdx.x;
  const int swz = (bid & 7) * (nwg >> 3) + (bid >> 3);
  const int tn = swz % ntiles, tm = swz / ntiles;
  const int m0 = tm << 8, n0 = tn * BN;
  const int wrm = (w >> 2) << 7;       // 0 / 128
  const int wcn = (w & 3) * WCN;

  const int kper = K / SK;
  const int kbeg = (SK > 1) ? (int)blockIdx.y * kper : 0;
  const int T = kper >> 6;
  OutT* __restrict__ C = C0;
  if constexpr (SK > 1) {
    const int sl = blockIdx.y;
    C = (sl == 0) ? C0 : (sl == 1) ? C1 : (sl == 2) ? C2 : C3;
  }

  // staging: issue i stages chunk c = w + i*8 (8 rows x 128B, 64 lanes x 16B)
  const int srow = lane >> 3;
  const int scol = ((lane & 7) ^ srow) << 3;   // pre-swizzled source col (shorts)
  const short* Ag[4]; const short* Bg[ISSB];
  #pragma unroll
  for (int i = 0; i < 4; ++i)
    Ag[i] = A + (size_t)(m0 + (w + i * 8) * 8 + srow) * K + kbeg + scol;
  #pragma unroll
  for (int i = 0; i < ISSB; ++i)
    Bg[i] = Bw + (size_t)(n0 + (w + i * 8) * 8 + srow) * K + kbeg + scol;

  f32x4 acc[8][NJ] = {};

  // prologue: tile 0 -> buf 0
  #pragma unroll
  for (int i = 0; i < 4; ++i) GLDS16(Ag[i], &Al[0][(w + i * 8) * 512]);
  #pragma unroll
  for (int i = 0; i < ISSB; ++i) GLDS16(Bg[i], &Bl[0][(w + i * 8) * 512]);

  for (int t = 0; t < T; ++t) {
    const int buf = t & 1;
    const bool more = (t + 1 < T);
    const int k1 = (t + 1) << 6;

    bf16x8 af[8], bfLo[NJH * 2], bfHi[NJH * 2];
    const int ph0 = lg ^ (lr & 7);        // ks=0 swizzled slot
    const int ph1 = (4 + lg) ^ (lr & 7);  // ks=1

    // ---- tile head: issue ALL of t+1; vmcnt drains only tile t's loads; barrier
    if (more) {
      #pragma unroll
      for (int i = 0; i < 4; ++i) GLDS16(Ag[i] + k1, &Al[buf ^ 1][(w + i * 8) * 512]);
      #pragma unroll
      for (int i = 0; i < ISSB; ++i) GLDS16(Bg[i] + k1, &Bl[buf ^ 1][(w + i * 8) * 512]);
      if constexpr (ISSB == 4) asm volatile("s_waitcnt vmcnt(8)" ::: "memory");
      else                     asm volatile("s_waitcnt vmcnt(6)" ::: "memory");
    } else {
      asm volatile("s_waitcnt vmcnt(0)" ::: "memory");
    }
    __builtin_amdgcn_sched_barrier(0);
    __builtin_amdgcn_s_barrier();

    // ---- one scheduling region: 16 ds_reads + 64 MFMA (no inner barriers)
    #pragma unroll
    for (int i = 0; i < 4; ++i) {
      const int R = wrm + i * 16 + lr;
      af[i * 2]     = *(const bf16x8*)&Al[buf][R * 64 + ph0 * 8];
      af[i * 2 + 1] = *(const bf16x8*)&Al[buf][R * 64 + ph1 * 8];
    }
    #pragma unroll
    for (int j = 0; j < NJH; ++j) {
      const int R = wcn + j * 16 + lr;
      bfLo[j * 2]     = *(const bf16x8*)&Bl[buf][R * 64 + ph0 * 8];
      bfLo[j * 2 + 1] = *(const bf16x8*)&Bl[buf][R * 64 + ph1 * 8];
    }
    __builtin_amdgcn_s_setprio(1);
    #pragma unroll
    for (int i = 0; i < 4; ++i)
      #pragma unroll
      for (int j = 0; j < NJH; ++j) {
        acc[i][j] = MFMA16(af[i * 2],     bfLo[j * 2],     acc[i][j]);
        acc[i][j] = MFMA16(af[i * 2 + 1], bfLo[j * 2 + 1], acc[i][j]);
      }
    __builtin_amdgcn_s_setprio(0);

    #pragma unroll
    for (int j = 0; j < NJH; ++j) {
      const int R = wcn + (j + NJH) * 16 + lr;
      bfHi[j * 2]     = *(const bf16x8*)&Bl[buf][R * 64 + ph0 * 8];
      bfHi[j * 2 + 1] = *(const bf16x8*)&Bl[buf][R * 64 + ph1 * 8];
    }
    __builtin_amdgcn_s_setprio(1);
    #pragma unroll
    for (int i = 0; i < 4; ++i)
      #pragma unroll
      for (int j = 0; j < NJH; ++j) {
        acc[i][j + NJH] = MFMA16(af[i * 2],     bfHi[j * 2],     acc[i][j + NJH]);
        acc[i][j + NJH] = MFMA16(af[i * 2 + 1], bfHi[j * 2 + 1], acc[i][j + NJH]);
      }
    __builtin_amdgcn_s_setprio(0);

    #pragma unroll
    for (int i = 0; i < 4; ++i) {
      const int R = wrm + (i + 4) * 16 + lr;
      af[i * 2]     = *(const bf16x8*)&Al[buf][R * 64 + ph0 * 8];
      af[i * 2 + 1] = *(const bf16x8*)&Al[buf][R * 64 + ph1 * 8];
    }
    __builtin_amdgcn_s_setprio(1);
    #pragma unroll
    for (int i = 0; i < 4; ++i)
      #pragma unroll
      for (int j = 0; j < NJH; ++j) {
        acc[i + 4][j + NJH] = MFMA16(af[i * 2],     bfHi[j * 2],     acc[i + 4][j + NJH]);
        acc[i + 4][j + NJH] = MFMA16(af[i * 2 + 1], bfHi[j * 2 + 1], acc[i + 4][j + NJH]);
      }
    #pragma unroll
    for (int i = 0; i < 4; ++i)
      #pragma unroll
      for (int j = 0; j < NJH; ++j) {
        acc[i + 4][j] = MFMA16(af[i * 2],     bfLo[j * 2],     acc[i + 4][j]);
        acc[i + 4][j] = MFMA16(af[i * 2 + 1], bfLo[j * 2 + 1], acc[i + 4][j]);
      }
    __builtin_amdgcn_s_setprio(0);

    // ---- tile boundary: all waves done reading buf before t+2's loads hit it
    __builtin_amdgcn_s_barrier();
  }

  // ---- epilogue
  #pragma unroll
  for (int j = 0; j < NJ; ++j) {
    const int col = n0 + wcn + j * 16 + lr;
    float bv = 0.f;
    if constexpr (EPI == 1) bv = bias[col];
    #pragma unroll
    for (int i = 0; i < 8; ++i) {
      #pragma unroll
      for (int r = 0; r < 4; ++r) {
        const int row = m0 + wrm + i * 16 + lg * 4 + r;
        float v = acc[i][j][r] + bv;
        if constexpr (EPI == 1) v = fmaxf(v, 0.f);
        if constexpr (sizeof(OutT) == 2) C[(size_t)row * N + col] = f2bf(v);
        else                             C[(size_t)row * N + col] = v;
      }
    }
  }
}

// ---------------------------------------------------------------- GEMM  C = A * Bw^T
// 128x128 tile, BK=32, double-buffered with counted vmcnt (round-8 verified).
template<int SK, int EPI, typename OutT>
__global__ __launch_bounds__(256) void gemm_bt(
    const short* __restrict__ A, const short* __restrict__ Bw,
    OutT* __restrict__ C0, OutT* __restrict__ C1, const float* __restrict__ bias,
    int M, int N, int K)
{
  __shared__ short Al[2][128 * 32];
  __shared__ short Bl[2][128 * 32];
  const int tid  = threadIdx.x;
  const int w    = tid >> 6, lane = tid & 63;
  const int ntiles = N >> 7;
  const int nwg = gridDim.x;
  const int bid = blockIdx.x;
  const int swz = (bid & 7) * (nwg >> 3) + (bid >> 3);
  const int tn = swz % ntiles, tm = swz / ntiles;
  const int m0 = tm << 7, n0 = tn << 7;
  const int wr = (w >> 1) << 6, wc = (w & 1) << 6;
  const int lr = lane & 15, lk = (lane >> 4) << 3;
  const int ra = lane >> 2, colA = (lane & 3) << 3;

  const int kper = K / SK;
  const int kbeg = (SK > 1) ? (int)blockIdx.y * kper : 0;
  const int T = kper >> 5;
  OutT* __restrict__ C = (SK > 1 && blockIdx.y) ? C1 : C0;

  const short* Ag0 = A  + (size_t)(m0 + w * 16 + ra) * K + colA;
  const short* Ag1 = A  + (size_t)(m0 + (w + 4) * 16 + ra) * K + colA;
  const short* Bg0 = Bw + (size_t)(n0 + w * 16 + ra) * K + colA;
  const short* Bg1 = Bw + (size_t)(n0 + (w + 4) * 16 + ra) * K + colA;

  f32x4 acc[4][4] = {};

  {
    const int k0 = kbeg;
    GLDS16(Ag0 + k0, &Al[0][w * 512]);
    GLDS16(Ag1 + k0, &Al[0][(w + 4) * 512]);
    GLDS16(Bg0 + k0, &Bl[0][w * 512]);
    GLDS16(Bg1 + k0, &Bl[0][(w + 4) * 512]);
  }

  for (int it = 0; it < T; ++it) {
    const int buf = it & 1;
    if (it + 1 < T) {
      const int k1 = kbeg + ((it + 1) << 5);
      GLDS16(Ag0 + k1, &Al[buf ^ 1][w * 512]);
      GLDS16(Ag1 + k1, &Al[buf ^ 1][(w + 4) * 512]);
      GLDS16(Bg0 + k1, &Bl[buf ^ 1][w * 512]);
      GLDS16(Bg1 + k1, &Bl[buf ^ 1][(w + 4) * 512]);
      asm volatile("s_waitcnt vmcnt(4)" ::: "memory");
    } else {
      asm volatile("s_waitcnt vmcnt(0)" ::: "memory");
    }
    __builtin_amdgcn_sched_barrier(0);
    __builtin_amdgcn_s_barrier();      // all waves' tile-it loads are in LDS

    bf16x8 af[4], bfr[4];
    #pragma unroll
    for (int i = 0; i < 4; ++i)
      af[i] = *(const bf16x8*)&Al[buf][(wr + i * 16 + lr) * 32 + lk];
    #pragma unroll
    for (int j = 0; j < 4; ++j)
      bfr[j] = *(const bf16x8*)&Bl[buf][(wc + j * 16 + lr) * 32 + lk];
    #pragma unroll
    for (int i = 0; i < 4; ++i)
      #pragma unroll
      for (int j = 0; j < 4; ++j)
        acc[i][j] = MFMA16(af[i], bfr[j], acc[i][j]);

    __builtin_amdgcn_s_barrier();      // readers done before iter it+1 overwrites buf
  }

  const int lg = lane >> 4;
  #pragma unroll
  for (int j = 0; j < 4; ++j) {
    const int col = n0 + wc + j * 16 + lr;
    float bv = 0.f;
    if constexpr (SK == 1 && EPI != 0) bv = bias[col];
    #pragma unroll
    for (int i = 0; i < 4; ++i) {
      #pragma unroll
      for (int r = 0; r < 4; ++r) {
        const int row = m0 + wr + i * 16 + lg * 4 + r;
        float v = acc[i][j][r] + bv;
        if constexpr (SK == 1 && EPI == 1) v = fmaxf(v, 0.f);
        if constexpr (sizeof(OutT) == 2) C[(size_t)row * N + col] = f2bf(v);
        else                             C[(size_t)row * N + col] = v;
      }
    }
  }
}

// ---------------------------------------------------------------- causal flash attention
// Round-12 verified: paired (p,31-p), 8 waves, K/V LDS double-buffer, 1 barrier/iter.
__global__ __launch_bounds__(512) void attn_kernel(
    const short* __restrict__ kqv, short* __restrict__ out)
{
  __shared__ short Kt[2][64][72];     // K rows (k) x d, double-buffered
  __shared__ short Vt[2][64][72];     // transposed: d x k, col k XOR-swizzled, dbuf
  __shared__ short Pl[8][16][72];     // per-wave P tile

  const int tid = threadIdx.x, w = tid >> 6, lane = tid & 63;
  const int wt = w & 3;               // wave index within its tile team
  const int p = blockIdx.x;           // 0..15, heaviest (p=0) dispatched first
  const int bh = blockIdx.y;          // 0..31
  const int b = bh >> 4, h = bh & 15;
  const int q0 = ((w < 4) ? (31 - p) : p) << 6;
  const int nkb = 32 - p;             // k-blocks for the hi tile (superset of lo's)
  const int lr = lane & 15, lg = lane >> 4;

  // Q fragment: rows q0 + wt*16 + lr, d = ks*32 + lg*8 ..+8; pre-scaled by 1/8 (exact)
  const size_t rowq = (size_t)(b * S_ + q0 + wt * 16 + lr) * 3072 + 1024 + h * 64;
  bf16x8 qf[2];
  qf[0] = *(const bf16x8*)&kqv[rowq + lg * 8];
  qf[1] = *(const bf16x8*)&kqv[rowq + 32 + lg * 8];
  #pragma unroll
  for (int ks = 0; ks < 2; ++ks)
    #pragma unroll
    for (int e = 0; e < 8; ++e)
      qf[ks][e] = f2bf(bf2f(qf[ks][e]) * 0.125f);

  f32x4 acc[4] = {};
  float m_run[4], l_run[4];
  #pragma unroll
  for (int r = 0; r < 4; ++r) { m_run[r] = -1e30f; l_run[r] = 0.f; }

  const int skk = tid >> 3;           // 0..63 staging row (k), one per 8 threads
  const int sc  = (tid & 7) << 3;     // staging col (d)
  const int vws = (tid & 7) << 3;     // V write swizzle: 8*((sc+e)>>3 & 7)
  const int vkc = skk ^ vws;          // V write column (swizzled)
  const short* gstage = kqv + (size_t)b * S_ * 3072 + h * 64 + sc;

  // prologue: tile 0 -> buf 0
  {
    bf16x8 kreg = *(const bf16x8*)&gstage[(size_t)skk * 3072];
    bf16x8 vreg = *(const bf16x8*)&gstage[(size_t)skk * 3072 + 2048];
    *(bf16x8*)&Kt[0][skk][sc] = kreg;
    #pragma unroll
    for (int e = 0; e < 8; ++e) Vt[0][sc + e][vkc] = vreg[e];
  }
  __syncthreads();

  for (int kbi = 0; kbi < nkb; ++kbi) {
    const int buf = kbi & 1;
    const int kb = kbi << 6;

    // ---- issue next tile's global loads (latency hides under process)
    bf16x8 kreg, vreg;
    const bool more = (kbi + 1 < nkb);
    if (more) {
      const size_t gb = (size_t)(((kbi + 1) << 6) + skk) * 3072;
      kreg = *(const bf16x8*)&gstage[gb];
      vreg = *(const bf16x8*)&gstage[gb + 2048];
    }

    // ---- per-wave processing on buf
    if (kb <= q0 + wt * 16 + 15) {
      f32x4 sacc[4] = {};
      __builtin_amdgcn_s_setprio(1);
      #pragma unroll
      for (int jt = 0; jt < 4; ++jt) {
        #pragma unroll
        for (int ks = 0; ks < 2; ++ks) {
          bf16x8 kf = *(const bf16x8*)&Kt[buf][jt * 16 + lr][ks * 32 + lg * 8];
          sacc[jt] = MFMA16(qf[ks], kf, sacc[jt]);
        }
      }
      __builtin_amdgcn_s_setprio(0);
      const bool full = (kb + 63 <= q0 + wt * 16);
      float rmax[4];
      if (full) {
        #pragma unroll
        for (int r = 0; r < 4; ++r)
          rmax[r] = fmaxf(fmaxf(sacc[0][r], sacc[1][r]), fmaxf(sacc[2][r], sacc[3][r]));
      } else {
        #pragma unroll
        for (int r = 0; r < 4; ++r) rmax[r] = -1e30f;
        #pragma unroll
        for (int jt = 0; jt < 4; ++jt) {
          const int kpos = kb + jt * 16 + lr;
          #pragma unroll
          for (int r = 0; r < 4; ++r) {
            const int qrow = q0 + wt * 16 + lg * 4 + r;
            float v = (kpos <= qrow) ? sacc[jt][r] : -1e30f;
            sacc[jt][r] = v;
            rmax[r] = fmaxf(rmax[r], v);
          }
        }
      }
      #pragma unroll
      for (int r = 0; r < 4; ++r) rmax[r] = dpp_max16(rmax[r]);
      int need = 0;
      #pragma unroll
      for (int r = 0; r < 4; ++r) need |= (rmax[r] > m_run[r] + 8.f) ? 1 : 0;
      if (__any(need)) {
        #pragma unroll
        for (int r = 0; r < 4; ++r) {
          const float mn = fmaxf(m_run[r], rmax[r]);
          const float al = exp2_hw((m_run[r] - mn) * LOG2E_);
          m_run[r] = mn;
          l_run[r] *= al;
          #pragma unroll
          for (int dt = 0; dt < 4; ++dt) acc[dt][r] *= al;
        }
      }
      float m2[4], rsum[4];
      #pragma unroll
      for (int r = 0; r < 4; ++r) { m2[r] = m_run[r] * LOG2E_; rsum[r] = 0.f; }
      #pragma unroll
      for (int jt = 0; jt < 4; ++jt)
        #pragma unroll
        for (int r = 0; r < 4; ++r) {
          const float pv = exp2_hw(__builtin_fmaf(sacc[jt][r], LOG2E_, -m2[r]));
          sacc[jt][r] = pv;
          rsum[r] += pv;
        }
      #pragma unroll
      for (int r = 0; r < 4; ++r) { rsum[r] = dpp_sum16(rsum[r]); l_run[r] += rsum[r]; }
      #pragma unroll
      for (int jt = 0; jt < 4; ++jt) {
        uint32_t w01, w23;
        asm("v_cvt_pk_bf16_f32 %0, %1, %2" : "=v"(w01) : "v"(sacc[jt][0]), "v"(sacc[jt][1]));
        asm("v_cvt_pk_bf16_f32 %0, %1, %2" : "=v"(w23) : "v"(sacc[jt][2]), "v"(sacc[jt][3]));
        Pl[w][lg * 4 + 0][jt * 16 + lr] = (short)(w01 & 0xffffu);
        Pl[w][lg * 4 + 1][jt * 16 + lr] = (short)(w01 >> 16);
        Pl[w][lg * 4 + 2][jt * 16 + lr] = (short)(w23 & 0xffffu);
        Pl[w][lg * 4 + 3][jt * 16 + lr] = (short)(w23 >> 16);
      }
      bf16x8 pa[2];
      pa[0] = *(const bf16x8*)&Pl[w][lr][lg * 8];
      pa[1] = *(const bf16x8*)&Pl[w][lr][32 + lg * 8];
      __builtin_amdgcn_s_setprio(1);
      #pragma unroll
      for (int dt = 0; dt < 4; ++dt) {
        const int vswz = (2 * dt + (lr >> 3)) << 3;
        #pragma unroll
        for (int ks = 0; ks < 2; ++ks) {
          bf16x8 vb = *(const bf16x8*)&Vt[buf][dt * 16 + lr][(ks * 32 + lg * 8) ^ vswz];
          acc[dt] = MFMA16(pa[ks], vb, acc[dt]);
        }
      }
      __builtin_amdgcn_s_setprio(0);
    }

    // ---- write prefetched tile into the other buffer
    if (more) {
      *(bf16x8*)&Kt[buf ^ 1][skk][sc] = kreg;
      #pragma unroll
      for (int e = 0; e < 8; ++e) Vt[buf ^ 1][sc + e][vkc] = vreg[e];
    }
    __syncthreads();   // orders: buf^1 writes before next read; buf reads before next write
  }

  // ---- epilogue: normalize and store (each wave owns unique rows)
  #pragma unroll
  for (int dt = 0; dt < 4; ++dt) {
    #pragma unroll
    for (int r = 0; r < 4; ++r) {
      const int d = h * 64 + dt * 16 + lr;
      const int q_row = q0 + wt * 16 + lg * 4 + r;
      out[(size_t)(b * S_ + q_row) * E_ + d] = f2bf(acc[dt][r] / l_run[r]);
    }
  }
}

// ---------------------------------------------------------------- residual + LayerNorm (2x f32 fold, proj)
template<int FINAL>
__global__ __launch_bounds__(256) void ln_kernel(
    const float* __restrict__ y0, const float* __restrict__ y1,
    const float* __restrict__ bias, const void* __restrict__ res,
    const float* __restrict__ gam, const float* __restrict__ bet,
    void* __restrict__ outp)
{
  const int row = blockIdx.x, tid = threadIdx.x, lane = tid & 63, w = tid >> 6;
  float4 a = ((const float4*)(y0 + (size_t)row * E_))[tid];
  float4 c = ((const float4*)(y1 + (size_t)row * E_))[tid];
  float r[4] = {a.x + c.x, a.y + c.y, a.z + c.z, a.w + c.w};
  if constexpr (FINAL) {
    float4 bi = ((const float4*)bias)[tid];
    shortx4 rb = ((const shortx4*)((const short*)res + (size_t)row * E_))[tid];
    r[0] += bi.x + bf2f(rb.x); r[1] += bi.y + bf2f(rb.y);
    r[2] += bi.z + bf2f(rb.z); r[3] += bi.w + bf2f(rb.w);
  } else {
    float4 rv = ((const float4*)((const float*)res + (size_t)row * E_))[tid];
    r[0] += rv.x; r[1] += rv.y; r[2] += rv.z; r[3] += rv.w;
  }
  float s  = r[0] + r[1] + r[2] + r[3];
  float ss = r[0]*r[0] + r[1]*r[1] + r[2]*r[2] + r[3]*r[3];
  #pragma unroll
  for (int m = 32; m >= 1; m >>= 1) { s += __shfl_xor(s, m); ss += __shfl_xor(ss, m); }
  __shared__ float red[8];
  if (lane == 0) { red[w] = s; red[4 + w] = ss; }
  __syncthreads();
  s  = red[0] + red[1] + red[2] + red[3];
  ss = red[4] + red[5] + red[6] + red[7];
  const float mu  = s * (1.f / E_);
  const float var = ss * (1.f / E_) - mu * mu;
  const float rs  = rsqrtf(var + 1e-6f);
  float4 gv = ((const float4*)gam)[tid];
  float4 bv = ((const float4*)bet)[tid];
  float o0 = (r[0] - mu) * rs * gv.x + bv.x;
  float o1 = (r[1] - mu) * rs * gv.y + bv.y;
  float o2 = (r[2] - mu) * rs * gv.z + bv.z;
  float o3 = (r[3] - mu) * rs * gv.w + bv.w;
  if constexpr (FINAL) {
    float4 o; o.x = o0; o.y = o1; o.z = o2; o.w = o3;
    ((float4*)((float*)outp + (size_t)row * E_))[tid] = o;
  } else {
    shortx4 o; o.x = f2bf(o0); o.y = f2bf(o1); o.z = f2bf(o2); o.w = f2bf(o3);
    ((shortx4*)((short*)outp + (size_t)row * E_))[tid] = o;
  }
}

// ---------------------------------------------------------------- final LN: fold 4 bf16 partials + bias + bf16 residual -> f32
__global__ __launch_bounds__(256) void ln_fold4(
    const short* __restrict__ y0, const short* __restrict__ y1,
    const short* __restrict__ y2, const short* __restrict__ y3,
    const float* __restrict__ bias, const short* __restrict__ res,
    const float* __restrict__ gam, const float* __restrict__ bet,
    float* __restrict__ outp)
{
  const int row = blockIdx.x, tid = threadIdx.x, lane = tid & 63, w = tid >> 6;
  const size_t base = (size_t)row * E_;
  shortx4 a0 = ((const shortx4*)(y0 + base))[tid];
  shortx4 a1 = ((const shortx4*)(y1 + base))[tid];
  shortx4 a2 = ((const shortx4*)(y2 + base))[tid];
  shortx4 a3 = ((const shortx4*)(y3 + base))[tid];
  shortx4 rb = ((const shortx4*)(res + base))[tid];
  float4 bi = ((const float4*)bias)[tid];
  float r[4];
  #pragma unroll
  for (int j = 0; j < 4; ++j)
    r[j] = bf2f(a0[j]) + bf2f(a1[j]) + bf2f(a2[j]) + bf2f(a3[j]) + bf2f(rb[j]);
  r[0] += bi.x; r[1] += bi.y; r[2] += bi.z; r[3] += bi.w;
  float s  = r[0] + r[1] + r[2] + r[3];
  float ss = r[0]*r[0] + r[1]*r[1] + r[2]*r[2] + r[3]*r[3];
  #pragma unroll
  for (int m = 32; m >= 1; m >>= 1) { s += __shfl_xor(s, m); ss += __shfl_xor(ss, m); }
  __shared__ float red[8];
  if (lane == 0) { red[w] = s; red[4 + w] = ss; }
  __syncthreads();
  s  = red[0] + red[1] + red[2] + red[3];
  ss = red[4] + red[5] + red[6] + red[7];
  const float mu  = s * (1.f / E_);
  const float var = ss * (1.f / E_) - mu * mu;
  const float rs  = rsqrtf(var + 1e-6f);
  float4 gv = ((const float4*)gam)[tid];
  float4 bv = ((const float4*)bet)[tid];
  float4 o;
  o.x = (r[0] - mu) * rs * gv.x + bv.x;
  o.y = (r[1] - mu) * rs * gv.y + bv.y;
  o.z = (r[2] - mu) * rs * gv.z + bv.z;
  o.w = (r[3] - mu) * rs * gv.w + bv.w;
  ((float4*)(outp + base))[tid] = o;
}

// ---------------------------------------------------------------- launch
// ws timeline (MB): [0-8 xb][8-14 wkqvb][14-16 wob][16-24 wupb][24-32 wdownb]
//   [32-56 kqv] -> attn [64-72 attno] -> proj [32-48 p0][48-64 p1] -> ln0 [72-80 xln]
//   -> up [32-64 hbuf] -> down (bf16 partials) [0-8 d0][8-16 d1][16-24 d2][64-72 d3]
//   -> ln_fold4.  Peak 96 MB.
extern "C" void kernel_launch(void* const* d_in, const int* in_sizes, int n_in,
                              void* d_out, int out_size, void* d_ws, size_t ws_size,
                              hipStream_t stream) {
  const float* x      = (const float*)d_in[0];
  const float* w_kqv  = (const float*)d_in[2];
  const float* w_o    = (const float*)d_in[3];
  const float* w_up   = (const float*)d_in[4];
  const float* b_up   = (const float*)d_in[5];
  const float* w_down = (const float*)d_in[6];
  const float* b_down = (const float*)d_in[7];
  const float* g1     = (const float*)d_in[8];
  const float* b1     = (const float*)d_in[9];
  const float* g2     = (const float*)d_in[10];
  const float* b2     = (const float*)d_in[11];
  float* out = (float*)d_out;

  char* ws = (char*)d_ws;
  short* xb     = (short*)(ws);
  short* wkqvb  = (short*)(ws + ((size_t)8  << 20));
  short* wob    = (short*)(ws + ((size_t)14 << 20));
  short* wupb   = (short*)(ws + ((size_t)16 << 20));
  short* wdownb = (short*)(ws + ((size_t)24 << 20));
  short* kqv    = (short*)(ws + ((size_t)32 << 20));
  float* proj0  = (float*)(ws + ((size_t)32 << 20));
  float* proj1  = (float*)(ws + ((size_t)48 << 20));
  short* hbuf   = (short*)(ws + ((size_t)32 << 20));
  short* attno  = (short*)(ws + ((size_t)64 << 20));
  short* xln    = (short*)(ws + ((size_t)72 << 20));
  short* dwn0   = (short*)(ws);                         // 0-8   (xb dead)
  short* dwn1   = (short*)(ws + ((size_t)8  << 20));    // 8-16  (wkqvb/wob dead)
  short* dwn2   = (short*)(ws + ((size_t)16 << 20));    // 16-24 (wupb dead)
  short* dwn3   = (short*)(ws + ((size_t)64 << 20));    // 64-72 (attno dead)

  cast_all<<<2048, 256, 0, stream>>>(x, w_kqv, w_o, w_up, w_down,
                                     xb, wkqvb, wob, wupb, wdownb);

  gemm_bt<1, 0, short><<<24 * 32, 256, 0, stream>>>(xb, wkqvb, kqv, nullptr, nullptr, M_, 3 * E_, E_);
  attn_kernel<<<dim3(16, B_ * H_), 512, 0, stream>>>(kqv, attno);
  gemm256_bt<128, 2, 0, float><<<dim3(128, 2), 512, 0, stream>>>(
      attno, wob, proj0, proj1, nullptr, nullptr, nullptr, M_, E_, E_);
  ln_kernel<0><<<M_, 256, 0, stream>>>(proj0, proj1, nullptr, x, g1, b1, xln);
  gemm256_bt<256, 1, 1, short><<<256, 512, 0, stream>>>(
      xln, wupb, hbuf, nullptr, nullptr, nullptr, b_up, M_, FF_, E_);
  gemm256_bt<256, 4, 0, short><<<dim3(64, 4), 512, 0, stream>>>(
      hbuf, wdownb, dwn0, dwn1, dwn2, dwn3, nullptr, M_, E_, FF_);
  ln_fold4<<<M_, 256, 0, stream>>>(dwn0, dwn1, dwn2, dwn3, b_down, xln, g2, b2, out);
}

// Round 18
// 223.943 us; speedup vs baseline: 1.0651x; 1.0224x over previous
//
#include <hip/hip_runtime.h>
#include <stdint.h>

#define B_ 2
#define S_ 2048
#define E_ 1024
#define H_ 16
#define HD_ 64
#define FF_ 4096
#define M_ 4096   // B*S
#define LOG2E_ 1.44269504f

typedef short bf16x8 __attribute__((ext_vector_type(8)));
typedef float f32x4  __attribute__((ext_vector_type(4)));
typedef short shortx4 __attribute__((ext_vector_type(4)));

#define MFMA16(a,b,c) __builtin_amdgcn_mfma_f32_16x16x32_bf16(a,b,c,0,0,0)

__device__ __forceinline__ short f2bf(float f) {
  uint32_t u = __builtin_bit_cast(uint32_t, f);
  u += 0x7fffu + ((u >> 16) & 1u);
  return (short)(u >> 16);
}
__device__ __forceinline__ float bf2f(short b) {
  uint32_t u = ((uint32_t)(uint16_t)b) << 16;
  return __builtin_bit_cast(float, u);
}
__device__ __forceinline__ float exp2_hw(float x) {
  float r;
  asm("v_exp_f32 %0, %1" : "=v"(r) : "v"(x));
  return r;
}

// DPP row-rotate (16-lane row), VALU-pipe cross-lane: ROW_ROR:N = 0x120|N
template<int CTRL>
__device__ __forceinline__ float dpp_ror(float x) {
  return __builtin_bit_cast(float,
    __builtin_amdgcn_update_dpp(0, __builtin_bit_cast(int, x), CTRL, 0xF, 0xF, true));
}
__device__ __forceinline__ float dpp_max16(float v) {
  v = fmaxf(v, dpp_ror<0x128>(v));
  v = fmaxf(v, dpp_ror<0x124>(v));
  v = fmaxf(v, dpp_ror<0x122>(v));
  v = fmaxf(v, dpp_ror<0x121>(v));
  return v;
}
__device__ __forceinline__ float dpp_sum16(float v) {
  v += dpp_ror<0x128>(v);
  v += dpp_ror<0x124>(v);
  v += dpp_ror<0x122>(v);
  v += dpp_ror<0x121>(v);
  return v;
}

// async global->LDS, 16B per lane, wave-uniform LDS base + lane*16 (per-lane global src)
#define GLDS16(g, l) __builtin_amdgcn_global_load_lds( \
    (const __attribute__((address_space(1))) unsigned int*)(g), \
    (__attribute__((address_space(3))) unsigned int*)(l), 16, 0, 0)

// ---------------------------------------------------------------- fused cast f32->bf16 (all 5 arrays)
__global__ void cast_all(const float* __restrict__ x, const float* __restrict__ wkqv,
                         const float* __restrict__ wo, const float* __restrict__ wup,
                         const float* __restrict__ wdown,
                         short* __restrict__ xb, short* __restrict__ wkqvb,
                         short* __restrict__ wob, short* __restrict__ wupb,
                         short* __restrict__ wdownb) {
  const int stride = gridDim.x * blockDim.x;
  for (int i = blockIdx.x * blockDim.x + threadIdx.x; i < 4194304; i += stride) {
    const int e = i << 2;
    const float* src; short* dst; int off;
    if (e < 4194304)       { src = x;     dst = xb;     off = e; }
    else if (e < 7340032)  { src = wkqv;  dst = wkqvb;  off = e - 4194304; }
    else if (e < 8388608)  { src = wo;    dst = wob;    off = e - 7340032; }
    else if (e < 12582912) { src = wup;   dst = wupb;   off = e - 8388608; }
    else                   { src = wdown; dst = wdownb; off = e - 12582912; }
    float4 v = *(const float4*)(src + off);
    shortx4 o;
    o.x = f2bf(v.x); o.y = f2bf(v.y); o.z = f2bf(v.z); o.w = f2bf(v.w);
    *(shortx4*)(dst + off) = o;
  }
}

// ---------------------------------------------------------------- GEMM 256xBN, BK=64, 8 waves
// Phase-structured, FULL-TILE prefetch, XOR-swizzled LDS, 2 barriers/tile
// (round-17 verified). BN in {256,128}. SK split-K -> C0..C3. EPI=1: bias+relu.
template<int BN, int SK, int EPI, typename OutT>
__global__ __launch_bounds__(512, 2) void gemm256_bt(
    const short* __restrict__ A, const short* __restrict__ Bw,
    OutT* __restrict__ C0, OutT* __restrict__ C1,
    OutT* __restrict__ C2, OutT* __restrict__ C3,
    const float* __restrict__ bias,
    int M, int N, int K)
{
  constexpr int WCN  = BN / 4;
  constexpr int NJ   = WCN / 16;
  constexpr int NJH  = NJ / 2;
  constexpr int ISSB = BN / 64;

  __shared__ short Al[2][256 * 64];
  __shared__ short Bl[2][BN * 64];
  const int tid = threadIdx.x;
  const int w = tid >> 6, lane = tid & 63;
  const int lr = lane & 15, lg = lane >> 4;
  const int ntiles = N / BN;
  const int nwg = gridDim.x;
  const int bid = blockIdx.x;
  const int swz = (bid & 7) * (nwg >> 3) + (bid >> 3);
  const int tn = swz % ntiles, tm = swz / ntiles;
  const int m0 = tm << 8, n0 = tn * BN;
  const int wrm = (w >> 2) << 7;
  const int wcn = (w & 3) * WCN;

  const int kper = K / SK;
  const int kbeg = (SK > 1) ? (int)blockIdx.y * kper : 0;
  const int T = kper >> 6;
  OutT* __restrict__ C = C0;
  if constexpr (SK > 1) {
    const int sl = blockIdx.y;
    C = (sl == 0) ? C0 : (sl == 1) ? C1 : (sl == 2) ? C2 : C3;
  }

  const int srow = lane >> 3;
  const int scol = ((lane & 7) ^ srow) << 3;   // pre-swizzled source col (shorts)
  const short* Ag[4]; const short* Bg[ISSB];
  #pragma unroll
  for (int i = 0; i < 4; ++i)
    Ag[i] = A + (size_t)(m0 + (w + i * 8) * 8 + srow) * K + kbeg + scol;
  #pragma unroll
  for (int i = 0; i < ISSB; ++i)
    Bg[i] = Bw + (size_t)(n0 + (w + i * 8) * 8 + srow) * K + kbeg + scol;

  f32x4 acc[8][NJ] = {};

  #pragma unroll
  for (int i = 0; i < 4; ++i) GLDS16(Ag[i], &Al[0][(w + i * 8) * 512]);
  #pragma unroll
  for (int i = 0; i < ISSB; ++i) GLDS16(Bg[i], &Bl[0][(w + i * 8) * 512]);

  for (int t = 0; t < T; ++t) {
    const int buf = t & 1;
    const bool more = (t + 1 < T);
    const int k1 = (t + 1) << 6;

    bf16x8 af[8], bfLo[NJH * 2], bfHi[NJH * 2];
    const int ph0 = lg ^ (lr & 7);
    const int ph1 = (4 + lg) ^ (lr & 7);

    if (more) {
      #pragma unroll
      for (int i = 0; i < 4; ++i) GLDS16(Ag[i] + k1, &Al[buf ^ 1][(w + i * 8) * 512]);
      #pragma unroll
      for (int i = 0; i < ISSB; ++i) GLDS16(Bg[i] + k1, &Bl[buf ^ 1][(w + i * 8) * 512]);
      if constexpr (ISSB == 4) asm volatile("s_waitcnt vmcnt(8)" ::: "memory");
      else                     asm volatile("s_waitcnt vmcnt(6)" ::: "memory");
    } else {
      asm volatile("s_waitcnt vmcnt(0)" ::: "memory");
    }
    __builtin_amdgcn_sched_barrier(0);
    __builtin_amdgcn_s_barrier();

    #pragma unroll
    for (int i = 0; i < 4; ++i) {
      const int R = wrm + i * 16 + lr;
      af[i * 2]     = *(const bf16x8*)&Al[buf][R * 64 + ph0 * 8];
      af[i * 2 + 1] = *(const bf16x8*)&Al[buf][R * 64 + ph1 * 8];
    }
    #pragma unroll
    for (int j = 0; j < NJH; ++j) {
      const int R = wcn + j * 16 + lr;
      bfLo[j * 2]     = *(const bf16x8*)&Bl[buf][R * 64 + ph0 * 8];
      bfLo[j * 2 + 1] = *(const bf16x8*)&Bl[buf][R * 64 + ph1 * 8];
    }
    __builtin_amdgcn_s_setprio(1);
    #pragma unroll
    for (int i = 0; i < 4; ++i)
      #pragma unroll
      for (int j = 0; j < NJH; ++j) {
        acc[i][j] = MFMA16(af[i * 2],     bfLo[j * 2],     acc[i][j]);
        acc[i][j] = MFMA16(af[i * 2 + 1], bfLo[j * 2 + 1], acc[i][j]);
      }
    __builtin_amdgcn_s_setprio(0);

    #pragma unroll
    for (int j = 0; j < NJH; ++j) {
      const int R = wcn + (j + NJH) * 16 + lr;
      bfHi[j * 2]     = *(const bf16x8*)&Bl[buf][R * 64 + ph0 * 8];
      bfHi[j * 2 + 1] = *(const bf16x8*)&Bl[buf][R * 64 + ph1 * 8];
    }
    __builtin_amdgcn_s_setprio(1);
    #pragma unroll
    for (int i = 0; i < 4; ++i)
      #pragma unroll
      for (int j = 0; j < NJH; ++j) {
        acc[i][j + NJH] = MFMA16(af[i * 2],     bfHi[j * 2],     acc[i][j + NJH]);
        acc[i][j + NJH] = MFMA16(af[i * 2 + 1], bfHi[j * 2 + 1], acc[i][j + NJH]);
      }
    __builtin_amdgcn_s_setprio(0);

    #pragma unroll
    for (int i = 0; i < 4; ++i) {
      const int R = wrm + (i + 4) * 16 + lr;
      af[i * 2]     = *(const bf16x8*)&Al[buf][R * 64 + ph0 * 8];
      af[i * 2 + 1] = *(const bf16x8*)&Al[buf][R * 64 + ph1 * 8];
    }
    __builtin_amdgcn_s_setprio(1);
    #pragma unroll
    for (int i = 0; i < 4; ++i)
      #pragma unroll
      for (int j = 0; j < NJH; ++j) {
        acc[i + 4][j + NJH] = MFMA16(af[i * 2],     bfHi[j * 2],     acc[i + 4][j + NJH]);
        acc[i + 4][j + NJH] = MFMA16(af[i * 2 + 1], bfHi[j * 2 + 1], acc[i + 4][j + NJH]);
      }
    #pragma unroll
    for (int i = 0; i < 4; ++i)
      #pragma unroll
      for (int j = 0; j < NJH; ++j) {
        acc[i + 4][j] = MFMA16(af[i * 2],     bfLo[j * 2],     acc[i + 4][j]);
        acc[i + 4][j] = MFMA16(af[i * 2 + 1], bfLo[j * 2 + 1], acc[i + 4][j]);
      }
    __builtin_amdgcn_s_setprio(0);

    __builtin_amdgcn_s_barrier();
  }

  #pragma unroll
  for (int j = 0; j < NJ; ++j) {
    const int col = n0 + wcn + j * 16 + lr;
    float bv = 0.f;
    if constexpr (EPI == 1) bv = bias[col];
    #pragma unroll
    for (int i = 0; i < 8; ++i) {
      #pragma unroll
      for (int r = 0; r < 4; ++r) {
        const int row = m0 + wrm + i * 16 + lg * 4 + r;
        float v = acc[i][j][r] + bv;
        if constexpr (EPI == 1) v = fmaxf(v, 0.f);
        if constexpr (sizeof(OutT) == 2) C[(size_t)row * N + col] = f2bf(v);
        else                             C[(size_t)row * N + col] = v;
      }
    }
  }
}

// ---------------------------------------------------------------- GEMM  C = A * Bw^T
// 128x128 tile, BK=32, double-buffered with counted vmcnt (round-8 verified).
template<int SK, int EPI, typename OutT>
__global__ __launch_bounds__(256) void gemm_bt(
    const short* __restrict__ A, const short* __restrict__ Bw,
    OutT* __restrict__ C0, OutT* __restrict__ C1, const float* __restrict__ bias,
    int M, int N, int K)
{
  __shared__ short Al[2][128 * 32];
  __shared__ short Bl[2][128 * 32];
  const int tid  = threadIdx.x;
  const int w    = tid >> 6, lane = tid & 63;
  const int ntiles = N >> 7;
  const int nwg = gridDim.x;
  const int bid = blockIdx.x;
  const int swz = (bid & 7) * (nwg >> 3) + (bid >> 3);
  const int tn = swz % ntiles, tm = swz / ntiles;
  const int m0 = tm << 7, n0 = tn << 7;
  const int wr = (w >> 1) << 6, wc = (w & 1) << 6;
  const int lr = lane & 15, lk = (lane >> 4) << 3;
  const int ra = lane >> 2, colA = (lane & 3) << 3;

  const int kper = K / SK;
  const int kbeg = (SK > 1) ? (int)blockIdx.y * kper : 0;
  const int T = kper >> 5;
  OutT* __restrict__ C = (SK > 1 && blockIdx.y) ? C1 : C0;

  const short* Ag0 = A  + (size_t)(m0 + w * 16 + ra) * K + colA;
  const short* Ag1 = A  + (size_t)(m0 + (w + 4) * 16 + ra) * K + colA;
  const short* Bg0 = Bw + (size_t)(n0 + w * 16 + ra) * K + colA;
  const short* Bg1 = Bw + (size_t)(n0 + (w + 4) * 16 + ra) * K + colA;

  f32x4 acc[4][4] = {};

  {
    const int k0 = kbeg;
    GLDS16(Ag0 + k0, &Al[0][w * 512]);
    GLDS16(Ag1 + k0, &Al[0][(w + 4) * 512]);
    GLDS16(Bg0 + k0, &Bl[0][w * 512]);
    GLDS16(Bg1 + k0, &Bl[0][(w + 4) * 512]);
  }

  for (int it = 0; it < T; ++it) {
    const int buf = it & 1;
    if (it + 1 < T) {
      const int k1 = kbeg + ((it + 1) << 5);
      GLDS16(Ag0 + k1, &Al[buf ^ 1][w * 512]);
      GLDS16(Ag1 + k1, &Al[buf ^ 1][(w + 4) * 512]);
      GLDS16(Bg0 + k1, &Bl[buf ^ 1][w * 512]);
      GLDS16(Bg1 + k1, &Bl[buf ^ 1][(w + 4) * 512]);
      asm volatile("s_waitcnt vmcnt(4)" ::: "memory");
    } else {
      asm volatile("s_waitcnt vmcnt(0)" ::: "memory");
    }
    __builtin_amdgcn_sched_barrier(0);
    __builtin_amdgcn_s_barrier();      // all waves' tile-it loads are in LDS

    bf16x8 af[4], bfr[4];
    #pragma unroll
    for (int i = 0; i < 4; ++i)
      af[i] = *(const bf16x8*)&Al[buf][(wr + i * 16 + lr) * 32 + lk];
    #pragma unroll
    for (int j = 0; j < 4; ++j)
      bfr[j] = *(const bf16x8*)&Bl[buf][(wc + j * 16 + lr) * 32 + lk];
    #pragma unroll
    for (int i = 0; i < 4; ++i)
      #pragma unroll
      for (int j = 0; j < 4; ++j)
        acc[i][j] = MFMA16(af[i], bfr[j], acc[i][j]);

    __builtin_amdgcn_s_barrier();      // readers done before iter it+1 overwrites buf
  }

  const int lg = lane >> 4;
  #pragma unroll
  for (int j = 0; j < 4; ++j) {
    const int col = n0 + wc + j * 16 + lr;
    float bv = 0.f;
    if constexpr (SK == 1 && EPI != 0) bv = bias[col];
    #pragma unroll
    for (int i = 0; i < 4; ++i) {
      #pragma unroll
      for (int r = 0; r < 4; ++r) {
        const int row = m0 + wr + i * 16 + lg * 4 + r;
        float v = acc[i][j][r] + bv;
        if constexpr (SK == 1 && EPI == 1) v = fmaxf(v, 0.f);
        if constexpr (sizeof(OutT) == 2) C[(size_t)row * N + col] = f2bf(v);
        else                             C[(size_t)row * N + col] = v;
      }
    }
  }
}

// ---------------------------------------------------------------- causal flash attention
// Round-12 verified math; Pl repacked to [8][16][64] with XOR-slot swizzle
// (phys 16B-slot = slot ^ (row&7)) -> LDS 53248 B -> 3 blocks/CU.
__global__ __launch_bounds__(512) void attn_kernel(
    const short* __restrict__ kqv, short* __restrict__ out)
{
  __shared__ short Kt[2][64][72];     // K rows (k) x d, double-buffered
  __shared__ short Vt[2][64][72];     // transposed: d x k, col k XOR-swizzled, dbuf
  __shared__ short Pl[8][16][64];     // per-wave P tile, XOR-slot swizzled

  const int tid = threadIdx.x, w = tid >> 6, lane = tid & 63;
  const int wt = w & 3;               // wave index within its tile team
  const int p = blockIdx.x;           // 0..15, heaviest (p=0) dispatched first
  const int bh = blockIdx.y;          // 0..31
  const int b = bh >> 4, h = bh & 15;
  const int q0 = ((w < 4) ? (31 - p) : p) << 6;
  const int nkb = 32 - p;             // k-blocks for the hi tile (superset of lo's)
  const int lr = lane & 15, lg = lane >> 4;

  // Q fragment: rows q0 + wt*16 + lr, d = ks*32 + lg*8 ..+8; pre-scaled by 1/8 (exact)
  const size_t rowq = (size_t)(b * S_ + q0 + wt * 16 + lr) * 3072 + 1024 + h * 64;
  bf16x8 qf[2];
  qf[0] = *(const bf16x8*)&kqv[rowq + lg * 8];
  qf[1] = *(const bf16x8*)&kqv[rowq + 32 + lg * 8];
  #pragma unroll
  for (int ks = 0; ks < 2; ++ks)
    #pragma unroll
    for (int e = 0; e < 8; ++e)
      qf[ks][e] = f2bf(bf2f(qf[ks][e]) * 0.125f);

  f32x4 acc[4] = {};
  float m_run[4], l_run[4];
  #pragma unroll
  for (int r = 0; r < 4; ++r) { m_run[r] = -1e30f; l_run[r] = 0.f; }

  const int skk = tid >> 3;           // 0..63 staging row (k), one per 8 threads
  const int sc  = (tid & 7) << 3;     // staging col (d)
  const int vws = (tid & 7) << 3;     // V write swizzle: 8*((sc+e)>>3 & 7)
  const int vkc = skk ^ vws;          // V write column (swizzled)
  const short* gstage = kqv + (size_t)b * S_ * 3072 + h * 64 + sc;

  // prologue: tile 0 -> buf 0
  {
    bf16x8 kreg = *(const bf16x8*)&gstage[(size_t)skk * 3072];
    bf16x8 vreg = *(const bf16x8*)&gstage[(size_t)skk * 3072 + 2048];
    *(bf16x8*)&Kt[0][skk][sc] = kreg;
    #pragma unroll
    for (int e = 0; e < 8; ++e) Vt[0][sc + e][vkc] = vreg[e];
  }
  __syncthreads();

  for (int kbi = 0; kbi < nkb; ++kbi) {
    const int buf = kbi & 1;
    const int kb = kbi << 6;

    // ---- issue next tile's global loads (latency hides under process)
    bf16x8 kreg, vreg;
    const bool more = (kbi + 1 < nkb);
    if (more) {
      const size_t gb = (size_t)(((kbi + 1) << 6) + skk) * 3072;
      kreg = *(const bf16x8*)&gstage[gb];
      vreg = *(const bf16x8*)&gstage[gb + 2048];
    }

    // ---- per-wave processing on buf
    if (kb <= q0 + wt * 16 + 15) {
      f32x4 sacc[4] = {};
      __builtin_amdgcn_s_setprio(1);
      #pragma unroll
      for (int jt = 0; jt < 4; ++jt) {
        #pragma unroll
        for (int ks = 0; ks < 2; ++ks) {
          bf16x8 kf = *(const bf16x8*)&Kt[buf][jt * 16 + lr][ks * 32 + lg * 8];
          sacc[jt] = MFMA16(qf[ks], kf, sacc[jt]);
        }
      }
      __builtin_amdgcn_s_setprio(0);
      const bool full = (kb + 63 <= q0 + wt * 16);
      float rmax[4];
      if (full) {
        #pragma unroll
        for (int r = 0; r < 4; ++r)
          rmax[r] = fmaxf(fmaxf(sacc[0][r], sacc[1][r]), fmaxf(sacc[2][r], sacc[3][r]));
      } else {
        #pragma unroll
        for (int r = 0; r < 4; ++r) rmax[r] = -1e30f;
        #pragma unroll
        for (int jt = 0; jt < 4; ++jt) {
          const int kpos = kb + jt * 16 + lr;
          #pragma unroll
          for (int r = 0; r < 4; ++r) {
            const int qrow = q0 + wt * 16 + lg * 4 + r;
            float v = (kpos <= qrow) ? sacc[jt][r] : -1e30f;
            sacc[jt][r] = v;
            rmax[r] = fmaxf(rmax[r], v);
          }
        }
      }
      #pragma unroll
      for (int r = 0; r < 4; ++r) rmax[r] = dpp_max16(rmax[r]);
      int need = 0;
      #pragma unroll
      for (int r = 0; r < 4; ++r) need |= (rmax[r] > m_run[r] + 8.f) ? 1 : 0;
      if (__any(need)) {
        #pragma unroll
        for (int r = 0; r < 4; ++r) {
          const float mn = fmaxf(m_run[r], rmax[r]);
          const float al = exp2_hw((m_run[r] - mn) * LOG2E_);
          m_run[r] = mn;
          l_run[r] *= al;
          #pragma unroll
          for (int dt = 0; dt < 4; ++dt) acc[dt][r] *= al;
        }
      }
      float m2[4], rsum[4];
      #pragma unroll
      for (int r = 0; r < 4; ++r) { m2[r] = m_run[r] * LOG2E_; rsum[r] = 0.f; }
      #pragma unroll
      for (int jt = 0; jt < 4; ++jt)
        #pragma unroll
        for (int r = 0; r < 4; ++r) {
          const float pv = exp2_hw(__builtin_fmaf(sacc[jt][r], LOG2E_, -m2[r]));
          sacc[jt][r] = pv;
          rsum[r] += pv;
        }
      #pragma unroll
      for (int r = 0; r < 4; ++r) { rsum[r] = dpp_sum16(rsum[r]); l_run[r] += rsum[r]; }
      // P -> LDS: slot = jt*2 + (lr>>3); phys = slot ^ (row&7); elem = lr&7
      #pragma unroll
      for (int jt = 0; jt < 4; ++jt) {
        uint32_t w01, w23;
        asm("v_cvt_pk_bf16_f32 %0, %1, %2" : "=v"(w01) : "v"(sacc[jt][0]), "v"(sacc[jt][1]));
        asm("v_cvt_pk_bf16_f32 %0, %1, %2" : "=v"(w23) : "v"(sacc[jt][2]), "v"(sacc[jt][3]));
        const int slot = jt * 2 + (lr >> 3);
        const int el = lr & 7;
        #pragma unroll
        for (int r = 0; r < 4; ++r) {
          const int row = lg * 4 + r;
          const uint32_t word = (r < 2) ? w01 : w23;
          const short val = (short)((r & 1) ? (word >> 16) : (word & 0xffffu));
          Pl[w][row][((slot ^ (row & 7)) << 3) + el] = val;
        }
      }
      bf16x8 pa[2];
      pa[0] = *(const bf16x8*)&Pl[w][lr][((0 * 4 + lg) ^ (lr & 7)) << 3];
      pa[1] = *(const bf16x8*)&Pl[w][lr][((1 * 4 + lg) ^ (lr & 7)) << 3];
      __builtin_amdgcn_s_setprio(1);
      #pragma unroll
      for (int dt = 0; dt < 4; ++dt) {
        const int vswz = (2 * dt + (lr >> 3)) << 3;
        #pragma unroll
        for (int ks = 0; ks < 2; ++ks) {
          bf16x8 vb = *(const bf16x8*)&Vt[buf][dt * 16 + lr][(ks * 32 + lg * 8) ^ vswz];
          acc[dt] = MFMA16(pa[ks], vb, acc[dt]);
        }
      }
      __builtin_amdgcn_s_setprio(0);
    }

    // ---- write prefetched tile into the other buffer
    if (more) {
      *(bf16x8*)&Kt[buf ^ 1][skk][sc] = kreg;
      #pragma unroll
      for (int e = 0; e < 8; ++e) Vt[buf ^ 1][sc + e][vkc] = vreg[e];
    }
    __syncthreads();   // orders: buf^1 writes before next read; buf reads before next write
  }

  // ---- epilogue: normalize and store (each wave owns unique rows)
  #pragma unroll
  for (int dt = 0; dt < 4; ++dt) {
    #pragma unroll
    for (int r = 0; r < 4; ++r) {
      const int d = h * 64 + dt * 16 + lr;
      const int q_row = q0 + wt * 16 + lg * 4 + r;
      out[(size_t)(b * S_ + q_row) * E_ + d] = f2bf(acc[dt][r] / l_run[r]);
    }
  }
}

// ---------------------------------------------------------------- LN: fold 2 bf16 partials + f32 residual -> bf16
__global__ __launch_bounds__(256) void ln_fold2(
    const short* __restrict__ y0, const short* __restrict__ y1,
    const float* __restrict__ res,
    const float* __restrict__ gam, const float* __restrict__ bet,
    short* __restrict__ outp)
{
  const int row = blockIdx.x, tid = threadIdx.x, lane = tid & 63, w = tid >> 6;
  const size_t base = (size_t)row * E_;
  shortx4 a0 = ((const shortx4*)(y0 + base))[tid];
  shortx4 a1 = ((const shortx4*)(y1 + base))[tid];
  float4 rv = ((const float4*)(res + base))[tid];
  float r[4];
  r[0] = bf2f(a0.x) + bf2f(a1.x) + rv.x;
  r[1] = bf2f(a0.y) + bf2f(a1.y) + rv.y;
  r[2] = bf2f(a0.z) + bf2f(a1.z) + rv.z;
  r[3] = bf2f(a0.w) + bf2f(a1.w) + rv.w;
  float s  = r[0] + r[1] + r[2] + r[3];
  float ss = r[0]*r[0] + r[1]*r[1] + r[2]*r[2] + r[3]*r[3];
  #pragma unroll
  for (int m = 32; m >= 1; m >>= 1) { s += __shfl_xor(s, m); ss += __shfl_xor(ss, m); }
  __shared__ float red[8];
  if (lane == 0) { red[w] = s; red[4 + w] = ss; }
  __syncthreads();
  s  = red[0] + red[1] + red[2] + red[3];
  ss = red[4] + red[5] + red[6] + red[7];
  const float mu  = s * (1.f / E_);
  const float var = ss * (1.f / E_) - mu * mu;
  const float rs  = rsqrtf(var + 1e-6f);
  float4 gv = ((const float4*)gam)[tid];
  float4 bv = ((const float4*)bet)[tid];
  shortx4 o;
  o.x = f2bf((r[0] - mu) * rs * gv.x + bv.x);
  o.y = f2bf((r[1] - mu) * rs * gv.y + bv.y);
  o.z = f2bf((r[2] - mu) * rs * gv.z + bv.z);
  o.w = f2bf((r[3] - mu) * rs * gv.w + bv.w);
  ((shortx4*)(outp + base))[tid] = o;
}

// ---------------------------------------------------------------- final LN: fold 4 bf16 partials + bias + bf16 residual -> f32
__global__ __launch_bounds__(256) void ln_fold4(
    const short* __restrict__ y0, const short* __restrict__ y1,
    const short* __restrict__ y2, const short* __restrict__ y3,
    const float* __restrict__ bias, const short* __restrict__ res,
    const float* __restrict__ gam, const float* __restrict__ bet,
    float* __restrict__ outp)
{
  const int row = blockIdx.x, tid = threadIdx.x, lane = tid & 63, w = tid >> 6;
  const size_t base = (size_t)row * E_;
  shortx4 a0 = ((const shortx4*)(y0 + base))[tid];
  shortx4 a1 = ((const shortx4*)(y1 + base))[tid];
  shortx4 a2 = ((const shortx4*)(y2 + base))[tid];
  shortx4 a3 = ((const shortx4*)(y3 + base))[tid];
  shortx4 rb = ((const shortx4*)(res + base))[tid];
  float4 bi = ((const float4*)bias)[tid];
  float r[4];
  #pragma unroll
  for (int j = 0; j < 4; ++j)
    r[j] = bf2f(a0[j]) + bf2f(a1[j]) + bf2f(a2[j]) + bf2f(a3[j]) + bf2f(rb[j]);
  r[0] += bi.x; r[1] += bi.y; r[2] += bi.z; r[3] += bi.w;
  float s  = r[0] + r[1] + r[2] + r[3];
  float ss = r[0]*r[0] + r[1]*r[1] + r[2]*r[2] + r[3]*r[3];
  #pragma unroll
  for (int m = 32; m >= 1; m >>= 1) { s += __shfl_xor(s, m); ss += __shfl_xor(ss, m); }
  __shared__ float red[8];
  if (lane == 0) { red[w] = s; red[4 + w] = ss; }
  __syncthreads();
  s  = red[0] + red[1] + red[2] + red[3];
  ss = red[4] + red[5] + red[6] + red[7];
  const float mu  = s * (1.f / E_);
  const float var = ss * (1.f / E_) - mu * mu;
  const float rs  = rsqrtf(var + 1e-6f);
  float4 gv = ((const float4*)gam)[tid];
  float4 bv = ((const float4*)bet)[tid];
  float4 o;
  o.x = (r[0] - mu) * rs * gv.x + bv.x;
  o.y = (r[1] - mu) * rs * gv.y + bv.y;
  o.z = (r[2] - mu) * rs * gv.z + bv.z;
  o.w = (r[3] - mu) * rs * gv.w + bv.w;
  ((float4*)(outp + base))[tid] = o;
}

// ---------------------------------------------------------------- launch
// ws timeline (MB): [0-8 xb][8-14 wkqvb][14-16 wob][16-24 wupb][24-32 wdownb]
//   [32-56 kqv] -> attn [64-72 attno] -> proj (bf16 partials) [32-40 p0][40-48 p1]
//   -> ln_fold2 [72-80 xln] -> up [32-64 hbuf]
//   -> down (bf16 partials) [0-8 d0][8-16 d1][16-24 d2][64-72 d3] -> ln_fold4.
extern "C" void kernel_launch(void* const* d_in, const int* in_sizes, int n_in,
                              void* d_out, int out_size, void* d_ws, size_t ws_size,
                              hipStream_t stream) {
  const float* x      = (const float*)d_in[0];
  const float* w_kqv  = (const float*)d_in[2];
  const float* w_o    = (const float*)d_in[3];
  const float* w_up   = (const float*)d_in[4];
  const float* b_up   = (const float*)d_in[5];
  const float* w_down = (const float*)d_in[6];
  const float* b_down = (const float*)d_in[7];
  const float* g1     = (const float*)d_in[8];
  const float* b1     = (const float*)d_in[9];
  const float* g2     = (const float*)d_in[10];
  const float* b2     = (const float*)d_in[11];
  float* out = (float*)d_out;

  char* ws = (char*)d_ws;
  short* xb     = (short*)(ws);
  short* wkqvb  = (short*)(ws + ((size_t)8  << 20));
  short* wob    = (short*)(ws + ((size_t)14 << 20));
  short* wupb   = (short*)(ws + ((size_t)16 << 20));
  short* wdownb = (short*)(ws + ((size_t)24 << 20));
  short* kqv    = (short*)(ws + ((size_t)32 << 20));
  short* proj0b = (short*)(ws + ((size_t)32 << 20));   // 32-40 (kqv dead after attn)
  short* proj1b = (short*)(ws + ((size_t)40 << 20));   // 40-48
  short* hbuf   = (short*)(ws + ((size_t)32 << 20));
  short* attno  = (short*)(ws + ((size_t)64 << 20));
  short* xln    = (short*)(ws + ((size_t)72 << 20));
  short* dwn0   = (short*)(ws);                         // 0-8   (xb dead)
  short* dwn1   = (short*)(ws + ((size_t)8  << 20));    // 8-16
  short* dwn2   = (short*)(ws + ((size_t)16 << 20));    // 16-24
  short* dwn3   = (short*)(ws + ((size_t)64 << 20));    // 64-72 (attno dead)

  cast_all<<<2048, 256, 0, stream>>>(x, w_kqv, w_o, w_up, w_down,
                                     xb, wkqvb, wob, wupb, wdownb);

  gemm_bt<1, 0, short><<<24 * 32, 256, 0, stream>>>(xb, wkqvb, kqv, nullptr, nullptr, M_, 3 * E_, E_);
  attn_kernel<<<dim3(16, B_ * H_), 512, 0, stream>>>(kqv, attno);
  gemm256_bt<128, 2, 0, short><<<dim3(128, 2), 512, 0, stream>>>(
      attno, wob, proj0b, proj1b, nullptr, nullptr, nullptr, M_, E_, E_);
  ln_fold2<<<M_, 256, 0, stream>>>(proj0b, proj1b, x, g1, b1, xln);
  gemm256_bt<256, 1, 1, short><<<256, 512, 0, stream>>>(
      xln, wupb, hbuf, nullptr, nullptr, nullptr, b_up, M_, FF_, E_);
  gemm256_bt<256, 4, 0, short><<<dim3(64, 4), 512, 0, stream>>>(
      hbuf, wdownb, dwn0, dwn1, dwn2, dwn3, nullptr, M_, E_, FF_);
  ln_fold4<<<M_, 256, 0, stream>>>(dwn0, dwn1, dwn2, dwn3, b_down, xln, g2, b2, out);
}